// Round 1
// baseline (1174.546 us; speedup 1.0000x reference)
//
#include <hip/hip_runtime.h>
#include <hip/hip_bf16.h>

// ---------------- precompute kernels ----------------

__global__ void degcnt_k(const int* __restrict__ col, const float* __restrict__ ew,
                         float* __restrict__ deg, int* __restrict__ cnti, int E) {
  int e = blockIdx.x * blockDim.x + threadIdx.x;
  if (e < E) {
    int c = col[e];
    atomicAdd(&deg[c], ew[e]);
    atomicAdd(&cnti[c], 1);
  }
}

__global__ void node_k(const float* __restrict__ deg, const int* __restrict__ cnti,
                       float* __restrict__ dinv, float* __restrict__ cntf, int n) {
  int i = blockIdx.x * blockDim.x + threadIdx.x;
  if (i < n) {
    float d = deg[i];
    dinv[i] = d > 0.f ? rsqrtf(d) : 0.f;
    cntf[i] = fmaxf((float)cnti[i], 1.f);
  }
}

// exclusive prefix sum of cnti over n (3-kernel scan), chunk = 1024/block
__global__ void scan1_k(const int* __restrict__ cnti, int* __restrict__ bsum, int n) {
  __shared__ int sd[256];
  int t = threadIdx.x, b = blockIdx.x;
  int base = b * 1024 + t * 4;
  int s = 0;
#pragma unroll
  for (int j = 0; j < 4; ++j) { int i = base + j; if (i < n) s += cnti[i]; }
  sd[t] = s; __syncthreads();
  for (int off = 128; off > 0; off >>= 1) {
    if (t < off) sd[t] += sd[t + off];
    __syncthreads();
  }
  if (t == 0) bsum[b] = sd[0];
}

__global__ void scan2_k(const int* __restrict__ bsum, int* __restrict__ boff, int B) {
  if (threadIdx.x == 0 && blockIdx.x == 0) {
    int acc = 0;
    for (int b = 0; b < B; ++b) { boff[b] = acc; acc += bsum[b]; }
  }
}

__global__ void scan3_k(const int* __restrict__ cnti, const int* __restrict__ boff,
                        int* __restrict__ offs, int* __restrict__ cursor, int n, int E) {
  __shared__ int sd[256];
  int t = threadIdx.x, b = blockIdx.x;
  int base = b * 1024 + t * 4;
  int v[4]; int s = 0;
#pragma unroll
  for (int j = 0; j < 4; ++j) { int i = base + j; v[j] = (i < n) ? cnti[i] : 0; s += v[j]; }
  sd[t] = s; __syncthreads();
  for (int off = 1; off < 256; off <<= 1) {
    int x = (t >= off) ? sd[t - off] : 0;
    __syncthreads();
    sd[t] += x;
    __syncthreads();
  }
  int excl = sd[t] - s + boff[b];
#pragma unroll
  for (int j = 0; j < 4; ++j) {
    int i = base + j;
    if (i < n) { offs[i] = excl; cursor[i] = excl; excl += v[j]; }
  }
  if (b == 0 && t == 0) offs[n] = E;
}

__global__ void fill_k(const int* __restrict__ row, const int* __restrict__ col,
                       const float* __restrict__ ew, const float* __restrict__ dinv,
                       int* __restrict__ cursor, int* __restrict__ srow,
                       float* __restrict__ snorm, float* __restrict__ sews, int E) {
  int e = blockIdx.x * blockDim.x + threadIdx.x;
  if (e < E) {
    int r = row[e], c = col[e];
    float wgt = ew[e];
    int pos = atomicAdd(&cursor[c], 1);
    srow[pos] = r;
    snorm[pos] = dinv[r] * wgt * dinv[c];
    sews[pos] = wgt;
  }
}

// ---------------- aggregation (CSR gather, both convs fused) ----------------
// outA[n] = sum_e norm_e * hp[row_e]; outS[n] = (sum_e ew_e * hp[row_e]) / cnt_n
__global__ void agg_k(const float* __restrict__ hp, const int* __restrict__ srow,
                      const float* __restrict__ snorm, const float* __restrict__ sews,
                      const int* __restrict__ offs, const float* __restrict__ cntf,
                      float* __restrict__ outA, float* __restrict__ outS) {
  int node = blockIdx.x;
  int f = threadIdx.x;  // 0..127
  int s0 = offs[node], e0 = offs[node + 1];
  float a = 0.f, m = 0.f;
  for (int ptr = s0; ptr < e0; ++ptr) {
    int r = srow[ptr];
    float v = hp[r * 128 + f];
    a += snorm[ptr] * v;
    m += sews[ptr] * v;
  }
  outA[node * 128 + f] = a;
  outS[node * 128 + f] = m / cntf[node];
}

// ---------------- fp32 GEMM: out = act(A1@W1 [+ A2@W2] + bias) ----------------
// A*: (nrows,128) row-major.  W*: (128,128) row-major.  out: (nrows,128).
// ACT: 0=none, 1=relu (leaky/elu no-ops on relu output), 2=fused elu(leaky_relu(x,0.01))
template <int ACT>
__global__ __launch_bounds__(256) void gemm128_k(
    const float* __restrict__ A1, const float* __restrict__ A2,
    const float* __restrict__ W1, const float* __restrict__ W2,
    const float* __restrict__ bias, float* __restrict__ out, int nrows) {
  __shared__ float As[64][36];    // 64 rows x 32-k chunk, pad to 36 (16B-aligned, conflict-light)
  __shared__ float Ws[32][128];   // 32-k chunk x 128 cols
  int t = threadIdx.x;
  int tx = t & 15, ty = t >> 4;
  int c0 = tx * 8, r0 = ty * 4;
  int rowBase = blockIdx.x * 64;
  float acc[4][8];
#pragma unroll
  for (int i = 0; i < 4; ++i)
#pragma unroll
    for (int j = 0; j < 8; ++j) acc[i][j] = 0.f;

  for (int src = 0; src < 2; ++src) {
    const float* A = src ? A2 : A1;
    const float* W = src ? W2 : W1;
    if (A == nullptr) break;
    for (int k0 = 0; k0 < 128; k0 += 32) {
      __syncthreads();
      // stage A tile: 64x32 floats = 512 float4, 2 per thread
#pragma unroll
      for (int i = 0; i < 2; ++i) {
        int f = t + i * 256;
        int r = f >> 3;
        int cq = (f & 7) * 4;
        float4 v = make_float4(0.f, 0.f, 0.f, 0.f);
        int gr = rowBase + r;
        if (gr < nrows) v = *(const float4*)&A[gr * 128 + k0 + cq];
        *(float4*)&As[r][cq] = v;
      }
      // stage W tile: 32x128 floats = 1024 float4, 4 per thread (fully coalesced)
#pragma unroll
      for (int i = 0; i < 4; ++i) {
        int f = t + i * 256;
        int kr = f >> 5;
        int cq = (f & 31) * 4;
        *(float4*)&Ws[kr][cq] = *(const float4*)&W[(k0 + kr) * 128 + cq];
      }
      __syncthreads();
#pragma unroll
      for (int k = 0; k < 32; ++k) {
        float aa[4];
        aa[0] = As[r0 + 0][k]; aa[1] = As[r0 + 1][k];
        aa[2] = As[r0 + 2][k]; aa[3] = As[r0 + 3][k];
        float4 b0 = *(const float4*)&Ws[k][c0];
        float4 b1 = *(const float4*)&Ws[k][c0 + 4];
        float bb[8] = {b0.x, b0.y, b0.z, b0.w, b1.x, b1.y, b1.z, b1.w};
#pragma unroll
        for (int i = 0; i < 4; ++i)
#pragma unroll
          for (int j = 0; j < 8; ++j) acc[i][j] += aa[i] * bb[j];
      }
    }
  }
#pragma unroll
  for (int i = 0; i < 4; ++i) {
    int gr = rowBase + r0 + i;
    if (gr < nrows) {
#pragma unroll
      for (int j = 0; j < 8; ++j) {
        float v = acc[i][j] + bias[c0 + j];
        if (ACT == 1) v = fmaxf(v, 0.f);
        if (ACT == 2) v = v > 0.f ? v : (__expf(0.01f * v) - 1.f);
        out[gr * 128 + c0 + j] = v;
      }
    }
  }
}

// ---------------- classifier: logits = [h1|h2]@cls_w + b; log_softmax ----------------
__global__ __launch_bounds__(256) void cls_k(const float* __restrict__ h1,
                                             const float* __restrict__ h2,
                                             const float* __restrict__ W,
                                             const float* __restrict__ b,
                                             float* __restrict__ out, int n) {
  __shared__ float hs[16][260];  // 16 nodes x 256 feats, pad 260 (stride%32==4 -> no conflicts)
  int t = threadIdx.x;
  int c = t & 15, nl = t >> 4;
  int n0 = blockIdx.x * 16;
  // cooperative staged load: 16 nodes x 64 float4
#pragma unroll
  for (int i = 0; i < 4; ++i) {
    int f = t + i * 256;
    int node = f >> 6;
    int q = f & 63;
    int gn = n0 + node;
    float4 v = make_float4(0.f, 0.f, 0.f, 0.f);
    if (gn < n)
      v = (q < 32) ? *(const float4*)&h1[gn * 128 + q * 4]
                   : *(const float4*)&h2[gn * 128 + (q - 32) * 4];
    *(float4*)&hs[node][q * 4] = v;
  }
  __syncthreads();
  float acc = b[c];
#pragma unroll 8
  for (int k = 0; k < 256; ++k) acc += hs[nl][k] * W[k * 16 + c];
  // log-softmax over the 16 class lanes (xor of bits 0..3 stays in group)
  float m = acc;
  for (int d = 1; d < 16; d <<= 1) m = fmaxf(m, __shfl_xor(m, d));
  float ex = __expf(acc - m);
  float sum = ex;
  for (int d = 1; d < 16; d <<= 1) sum += __shfl_xor(sum, d);
  float r = (acc - m) - logf(sum);
  int gn = n0 + nl;
  if (gn < n) out[gn * 16 + c] = r;
}

// ---------------- launch ----------------

extern "C" void kernel_launch(void* const* d_in, const int* in_sizes, int n_in,
                              void* d_out, int out_size, void* d_ws, size_t ws_size,
                              hipStream_t stream) {
  const float* x        = (const float*)d_in[0];
  const int*   eidx     = (const int*)d_in[1];
  const float* ew       = (const float*)d_in[2];
  const float* pre_w0   = (const float*)d_in[3];
  const float* pre_b0   = (const float*)d_in[4];
  const float* arma_w0  = (const float*)d_in[5];
  const float* arma_v0  = (const float*)d_in[6];
  const float* arma_b0  = (const float*)d_in[7];
  const float* sage_wl0 = (const float*)d_in[8];
  const float* sage_bl0 = (const float*)d_in[9];
  const float* sage_wr0 = (const float*)d_in[10];
  const float* pre_w1   = (const float*)d_in[11];
  const float* pre_b1   = (const float*)d_in[12];
  const float* arma_w1  = (const float*)d_in[13];
  const float* arma_v1  = (const float*)d_in[14];
  const float* arma_b1  = (const float*)d_in[15];
  const float* sage_wl1 = (const float*)d_in[16];
  const float* sage_bl1 = (const float*)d_in[17];
  const float* sage_wr1 = (const float*)d_in[18];
  const float* cls_w    = (const float*)d_in[19];
  const float* cls_b    = (const float*)d_in[20];

  const int N = in_sizes[0] / 128;
  const int E = in_sizes[2];
  const int* row = eidx;
  const int* col = eidx + E;

  char* p = (char*)d_ws;
  auto carve = [&](size_t bytes) { char* q = p; p += (bytes + 255) & ~(size_t)255; return q; };
  float* hp    = (float*)carve((size_t)N * 128 * 4);
  float* bufA  = (float*)carve((size_t)N * 128 * 4);
  float* bufS  = (float*)carve((size_t)N * 128 * 4);
  int*   srow  = (int*)carve((size_t)E * 4);
  float* snorm = (float*)carve((size_t)E * 4);
  float* sews  = (float*)carve((size_t)E * 4);
  float* deg   = (float*)carve((size_t)N * 4);
  float* dinv  = (float*)carve((size_t)N * 4);
  float* cntf  = (float*)carve((size_t)N * 4);
  int*   cnti  = (int*)carve((size_t)N * 4);
  int*   offs  = (int*)carve((size_t)(N + 1) * 4);
  int*   cursor= (int*)carve((size_t)N * 4);
  const int B  = (N + 1023) / 1024;
  int*   bsum  = (int*)carve((size_t)B * 4);
  int*   boff  = (int*)carve((size_t)B * 4);

  hipMemsetAsync(deg, 0, (size_t)N * 4, stream);
  hipMemsetAsync(cnti, 0, (size_t)N * 4, stream);

  degcnt_k<<<(E + 255) / 256, 256, 0, stream>>>(col, ew, deg, cnti, E);
  node_k<<<(N + 255) / 256, 256, 0, stream>>>(deg, cnti, dinv, cntf, N);
  scan1_k<<<B, 256, 0, stream>>>(cnti, bsum, N);
  scan2_k<<<1, 64, 0, stream>>>(bsum, boff, B);
  scan3_k<<<B, 256, 0, stream>>>(cnti, boff, offs, cursor, N, E);
  fill_k<<<(E + 255) / 256, 256, 0, stream>>>(row, col, ew, dinv, cursor, srow, snorm, sews, E);

  const int gB = (N + 63) / 64;
  // ---- cell 0 ----
  gemm128_k<0><<<gB, 256, 0, stream>>>(x, nullptr, pre_w0, nullptr, pre_b0, hp, N);
  agg_k<<<N, 128, 0, stream>>>(hp, srow, snorm, sews, offs, cntf, bufA, bufS);
  // h1 = relu(aggA@arma_w + hp@arma_v + arma_b)   (leaky/elu are no-ops on relu output)
  gemm128_k<1><<<gB, 256, 0, stream>>>(bufA, hp, arma_w0, arma_v0, arma_b0, bufA, N);
  // h2 = elu(leaky(smean@wl + hp@wr + bl))
  gemm128_k<2><<<gB, 256, 0, stream>>>(bufS, hp, sage_wl0, sage_wr0, sage_bl0, bufS, N);
  // ---- cell 1 ----  (pre: concat(h1,h2)@pre_w1 via dual-GEMM)
  gemm128_k<0><<<gB, 256, 0, stream>>>(bufA, bufS, pre_w1, pre_w1 + 128 * 128, pre_b1, hp, N);
  agg_k<<<N, 128, 0, stream>>>(hp, srow, snorm, sews, offs, cntf, bufA, bufS);
  gemm128_k<1><<<gB, 256, 0, stream>>>(bufA, hp, arma_w1, arma_v1, arma_b1, bufA, N);
  gemm128_k<2><<<gB, 256, 0, stream>>>(bufS, hp, sage_wl1, sage_wr1, sage_bl1, bufS, N);
  // ---- classifier ----
  cls_k<<<(N + 15) / 16, 256, 0, stream>>>(bufA, bufS, cls_w, cls_b, (float*)d_out, N);
}

// Round 2
// 811.915 us; speedup vs baseline: 1.4466x; 1.4466x over previous
//
#include <hip/hip_runtime.h>
#include <hip/hip_bf16.h>

typedef __bf16 bf16x8 __attribute__((ext_vector_type(8)));
typedef float f32x4 __attribute__((ext_vector_type(4)));
typedef unsigned short ushort_t;
typedef unsigned int uint_t;

// ---- bf16 helpers (storage = ushort) ----
__device__ inline float blo(uint_t v) { return __uint_as_float(v << 16); }
__device__ inline float bhi(uint_t v) { return __uint_as_float(v & 0xffff0000u); }
__device__ inline ushort_t f2b(float f) {  // RTNE
  uint_t u = __float_as_uint(f);
  uint_t r = (u + 0x7fffu + ((u >> 16) & 1u)) >> 16;
  return (ushort_t)r;
}
__device__ inline uint_t pk2(float a, float b) {
  return (uint_t)f2b(a) | ((uint_t)f2b(b) << 16);
}

// ---------------- precompute kernels ----------------

__global__ void degcnt_k(const int* __restrict__ col, const float* __restrict__ ew,
                         float* __restrict__ deg, int* __restrict__ cnti, int E) {
  int e = blockIdx.x * blockDim.x + threadIdx.x;
  if (e < E) {
    int c = col[e];
    atomicAdd(&deg[c], ew[e]);
    atomicAdd(&cnti[c], 1);
  }
}

__global__ void node_k(const float* __restrict__ deg, const int* __restrict__ cnti,
                       float* __restrict__ dinv, float* __restrict__ cinv, int n) {
  int i = blockIdx.x * blockDim.x + threadIdx.x;
  if (i < n) {
    float d = deg[i];
    dinv[i] = d > 0.f ? rsqrtf(d) : 0.f;
    cinv[i] = 1.0f / fmaxf((float)cnti[i], 1.f);
  }
}

__global__ void scan1_k(const int* __restrict__ cnti, int* __restrict__ bsum, int n) {
  __shared__ int sd[256];
  int t = threadIdx.x, b = blockIdx.x;
  int base = b * 1024 + t * 4;
  int s = 0;
#pragma unroll
  for (int j = 0; j < 4; ++j) { int i = base + j; if (i < n) s += cnti[i]; }
  sd[t] = s; __syncthreads();
  for (int off = 128; off > 0; off >>= 1) {
    if (t < off) sd[t] += sd[t + off];
    __syncthreads();
  }
  if (t == 0) bsum[b] = sd[0];
}

__global__ void scan2_k(const int* __restrict__ bsum, int* __restrict__ boff, int B) {
  if (threadIdx.x == 0 && blockIdx.x == 0) {
    int acc = 0;
    for (int b = 0; b < B; ++b) { boff[b] = acc; acc += bsum[b]; }
  }
}

__global__ void scan3_k(const int* __restrict__ cnti, const int* __restrict__ boff,
                        int* __restrict__ offs, int* __restrict__ cursor, int n, int E) {
  __shared__ int sd[256];
  int t = threadIdx.x, b = blockIdx.x;
  int base = b * 1024 + t * 4;
  int v[4]; int s = 0;
#pragma unroll
  for (int j = 0; j < 4; ++j) { int i = base + j; v[j] = (i < n) ? cnti[i] : 0; s += v[j]; }
  sd[t] = s; __syncthreads();
  for (int off = 1; off < 256; off <<= 1) {
    int x = (t >= off) ? sd[t - off] : 0;
    __syncthreads();
    sd[t] += x;
    __syncthreads();
  }
  int excl = sd[t] - s + boff[b];
#pragma unroll
  for (int j = 0; j < 4; ++j) {
    int i = base + j;
    if (i < n) { offs[i] = excl; cursor[i] = excl; excl += v[j]; }
  }
  if (b == 0 && t == 0) offs[n] = E;
}

// meta = {sym-norm, ew/cnt[col]} packed per edge (sorted by col)
__global__ void fill_k(const int* __restrict__ row, const int* __restrict__ col,
                       const float* __restrict__ ew, const float* __restrict__ dinv,
                       const float* __restrict__ cinv, int* __restrict__ cursor,
                       int* __restrict__ srow, float2* __restrict__ smeta, int E) {
  int e = blockIdx.x * blockDim.x + threadIdx.x;
  if (e < E) {
    int r = row[e], c = col[e];
    float wgt = ew[e];
    int pos = atomicAdd(&cursor[c], 1);
    srow[pos] = r;
    smeta[pos] = make_float2(dinv[r] * wgt * dinv[c], wgt * cinv[c]);
  }
}

// ---------------- convert x to bf16 ----------------
__global__ void cvt_k(const float* __restrict__ in, uint_t* __restrict__ out, int n4) {
  int i = blockIdx.x * blockDim.x + threadIdx.x;
  if (i < n4) {
    float4 v = *(const float4*)&in[(size_t)i * 4];
    out[(size_t)i * 2]     = pk2(v.x, v.y);
    out[(size_t)i * 2 + 1] = pk2(v.z, v.w);
  }
}

// ---------------- weight transpose+convert: Wt[c][k] = bf16(W[k][c]) ----------------
struct WP { const float* p[11]; };
__global__ void wtp_k(WP wp, ushort_t* __restrict__ wt) {
  int b = blockIdx.x;
  const float* W = wp.p[b];
  ushort_t* T = wt + (size_t)b * 128 * 128;
  for (int i = 0; i < 64; ++i) {
    int lin = i * 256 + threadIdx.x;
    int k = lin >> 7, c = lin & 127;
    T[c * 128 + k] = f2b(W[lin]);
  }
}

// ---------------- aggregation: one wave per node, bf16 rows ----------------
// outA = sum norm*h[row]; outS = sum (ew/cnt)*h[row]
__global__ __launch_bounds__(256) void agg_k(
    const uint_t* __restrict__ hp2, const int* __restrict__ srow,
    const float2* __restrict__ smeta, const int* __restrict__ offs,
    uint_t* __restrict__ outA, uint_t* __restrict__ outS, int n) {
  int wid = threadIdx.x >> 6;
  int lane = threadIdx.x & 63;
  int node = blockIdx.x * 4 + wid;
  if (node >= n) return;
  int s0 = offs[node], e0 = offs[node + 1];
  float a0 = 0.f, a1 = 0.f, m0 = 0.f, m1 = 0.f;
  for (int p = s0; p < e0; ++p) {
    int r = srow[p];
    float2 w = smeta[p];
    uint_t v = hp2[(size_t)r * 64 + lane];
    float f0 = blo(v), f1 = bhi(v);
    a0 += w.x * f0; a1 += w.x * f1;
    m0 += w.y * f0; m1 += w.y * f1;
  }
  outA[(size_t)node * 64 + lane] = pk2(a0, a1);
  outS[(size_t)node * 64 + lane] = pk2(m0, m1);
}

// ---------------- MFMA bf16 GEMM: out = act(A1@W1 [+ A2@W2] + bias) ----------------
// A*: (nrows,128) bf16 row-major. Wt*: (128,128) bf16, Wt[c][k]=W[k][c]. out bf16.
// ACT: 0=none, 1=relu, 2=elu(leaky_relu(x,0.01))
__device__ inline int swz(int r, int k) { return (r * 128 + k) ^ ((r & 7) << 3); }

template <int ACT, int NSRC>
__global__ __launch_bounds__(256) void mgemm_k(
    const ushort_t* __restrict__ A1, const ushort_t* __restrict__ A2,
    const ushort_t* __restrict__ Wt1, const ushort_t* __restrict__ Wt2,
    const float* __restrict__ bias, ushort_t* __restrict__ out, int nrows) {
  __shared__ ushort_t As[128 * 128];
  __shared__ ushort_t Ws[128 * 128];
  int t = threadIdx.x;
  int lane = t & 63, wid = t >> 6;
  int wr = wid >> 1, wc = wid & 1;   // 2x2 wave grid, each wave 64x64
  int rowBase = blockIdx.x * 128;
  f32x4 acc[4][4] = {};

#pragma unroll
  for (int src = 0; src < NSRC; ++src) {
    const ushort_t* A = src ? A2 : A1;
    const ushort_t* Wt = src ? Wt2 : Wt1;
    __syncthreads();
    // stage A (128x128 bf16) + Wt (128x128 bf16), 16B per thread per pass
#pragma unroll
    for (int i = 0; i < 8; ++i) {
      int f = t + i * 256;
      int r = f >> 4;
      int kq = (f & 15) * 8;
      int gr = rowBase + r;
      uint4 v = make_uint4(0, 0, 0, 0);
      if (gr < nrows) v = *(const uint4*)&A[(size_t)gr * 128 + kq];
      *(uint4*)&As[swz(r, kq)] = v;
      *(uint4*)&Ws[swz(r, kq)] = *(const uint4*)&Wt[(size_t)r * 128 + kq];
    }
    __syncthreads();
#pragma unroll
    for (int k = 0; k < 4; ++k) {
      bf16x8 af[4], bfr[4];
#pragma unroll
      for (int m = 0; m < 4; ++m)
        af[m] = *(const bf16x8*)&As[swz(wr * 64 + m * 16 + (lane & 15), k * 32 + (lane >> 4) * 8)];
#pragma unroll
      for (int nn = 0; nn < 4; ++nn)
        bfr[nn] = *(const bf16x8*)&Ws[swz(wc * 64 + nn * 16 + (lane & 15), k * 32 + (lane >> 4) * 8)];
#pragma unroll
      for (int m = 0; m < 4; ++m)
#pragma unroll
        for (int nn = 0; nn < 4; ++nn)
          acc[m][nn] = __builtin_amdgcn_mfma_f32_16x16x32_bf16(af[m], bfr[nn], acc[m][nn], 0, 0, 0);
    }
  }
  // epilogue: C/D layout col=lane&15, row=(lane>>4)*4+j
#pragma unroll
  for (int m = 0; m < 4; ++m) {
    int gr0 = rowBase + wr * 64 + m * 16 + (lane >> 4) * 4;
#pragma unroll
    for (int nn = 0; nn < 4; ++nn) {
      int gc = wc * 64 + nn * 16 + (lane & 15);
      float bv = bias[gc];
#pragma unroll
      for (int j = 0; j < 4; ++j) {
        int gr = gr0 + j;
        if (gr < nrows) {
          float v = acc[m][nn][j] + bv;
          if (ACT == 1) v = fmaxf(v, 0.f);
          if (ACT == 2) v = v > 0.f ? v : (__expf(0.01f * v) - 1.f);
          out[(size_t)gr * 128 + gc] = f2b(v);
        }
      }
    }
  }
}

// ---------------- classifier ----------------
__global__ __launch_bounds__(256) void cls_k(
    const ushort_t* __restrict__ h1, const ushort_t* __restrict__ h2,
    const float* __restrict__ W, const float* __restrict__ b,
    float* __restrict__ out, int n) {
  __shared__ float hs[16][260];
  int t = threadIdx.x;
  int c = t & 15, nl = t >> 4;
  int n0 = blockIdx.x * 16;
#pragma unroll
  for (int i = 0; i < 2; ++i) {
    int f = t + i * 256;
    int node = f >> 5;   // 32 uint4 per node (16 h1 + 16 h2)
    int q = f & 31;
    int gn = n0 + node;
    uint4 v = make_uint4(0, 0, 0, 0);
    if (gn < n)
      v = (q < 16) ? *(const uint4*)&h1[(size_t)gn * 128 + q * 8]
                   : *(const uint4*)&h2[(size_t)gn * 128 + (q - 16) * 8];
    int base = q * 8;  // q<16 -> 0..127 ; q>=16 -> 128..255
    uint_t u[4] = {v.x, v.y, v.z, v.w};
#pragma unroll
    for (int j = 0; j < 4; ++j) {
      hs[node][base + 2 * j]     = blo(u[j]);
      hs[node][base + 2 * j + 1] = bhi(u[j]);
    }
  }
  __syncthreads();
  float acc = b[c];
#pragma unroll 8
  for (int k = 0; k < 256; ++k) acc += hs[nl][k] * W[k * 16 + c];
  float mx = acc;
  for (int d = 1; d < 16; d <<= 1) mx = fmaxf(mx, __shfl_xor(mx, d));
  float ex = __expf(acc - mx);
  float sum = ex;
  for (int d = 1; d < 16; d <<= 1) sum += __shfl_xor(sum, d);
  float r = (acc - mx) - logf(sum);
  int gn = n0 + nl;
  if (gn < n) out[gn * 16 + c] = r;
}

// ---------------- launch ----------------

extern "C" void kernel_launch(void* const* d_in, const int* in_sizes, int n_in,
                              void* d_out, int out_size, void* d_ws, size_t ws_size,
                              hipStream_t stream) {
  const float* x        = (const float*)d_in[0];
  const int*   eidx     = (const int*)d_in[1];
  const float* ew       = (const float*)d_in[2];
  const float* pre_w0   = (const float*)d_in[3];
  const float* pre_b0   = (const float*)d_in[4];
  const float* arma_w0  = (const float*)d_in[5];
  const float* arma_v0  = (const float*)d_in[6];
  const float* arma_b0  = (const float*)d_in[7];
  const float* sage_wl0 = (const float*)d_in[8];
  const float* sage_bl0 = (const float*)d_in[9];
  const float* sage_wr0 = (const float*)d_in[10];
  const float* pre_w1   = (const float*)d_in[11];
  const float* pre_b1   = (const float*)d_in[12];
  const float* arma_w1  = (const float*)d_in[13];
  const float* arma_v1  = (const float*)d_in[14];
  const float* arma_b1  = (const float*)d_in[15];
  const float* sage_wl1 = (const float*)d_in[16];
  const float* sage_bl1 = (const float*)d_in[17];
  const float* sage_wr1 = (const float*)d_in[18];
  const float* cls_w    = (const float*)d_in[19];
  const float* cls_b    = (const float*)d_in[20];

  const int N = in_sizes[0] / 128;
  const int E = in_sizes[2];
  const int* row = eidx;
  const int* col = eidx + E;

  char* p = (char*)d_ws;
  auto carve = [&](size_t bytes) { char* q = p; p += (bytes + 255) & ~(size_t)255; return q; };
  ushort_t* hp    = (ushort_t*)carve((size_t)N * 128 * 2);
  ushort_t* bufA  = (ushort_t*)carve((size_t)N * 128 * 2);
  ushort_t* bufS  = (ushort_t*)carve((size_t)N * 128 * 2);
  ushort_t* xb    = (ushort_t*)carve((size_t)N * 128 * 2);
  ushort_t* wt    = (ushort_t*)carve((size_t)11 * 128 * 128 * 2);
  int*    srow  = (int*)carve((size_t)E * 4);
  float2* smeta = (float2*)carve((size_t)E * 8);
  float*  deg   = (float*)carve((size_t)N * 4);
  float*  dinv  = (float*)carve((size_t)N * 4);
  float*  cinv  = (float*)carve((size_t)N * 4);
  int*    cnti  = (int*)carve((size_t)N * 4);
  int*    offs  = (int*)carve((size_t)(N + 1) * 4);
  int*    cursor= (int*)carve((size_t)N * 4);
  const int B   = (N + 1023) / 1024;
  int*    bsum  = (int*)carve((size_t)B * 4);
  int*    boff  = (int*)carve((size_t)B * 4);

  hipMemsetAsync(deg, 0, (size_t)N * 4, stream);
  hipMemsetAsync(cnti, 0, (size_t)N * 4, stream);

  degcnt_k<<<(E + 255) / 256, 256, 0, stream>>>(col, ew, deg, cnti, E);
  node_k<<<(N + 255) / 256, 256, 0, stream>>>(deg, cnti, dinv, cinv, N);
  scan1_k<<<B, 256, 0, stream>>>(cnti, bsum, N);
  scan2_k<<<1, 64, 0, stream>>>(bsum, boff, B);
  scan3_k<<<B, 256, 0, stream>>>(cnti, boff, offs, cursor, N, E);
  fill_k<<<(E + 255) / 256, 256, 0, stream>>>(row, col, ew, dinv, cinv, cursor, srow, smeta, E);

  cvt_k<<<(N * 128 / 4 + 255) / 256, 256, 0, stream>>>(x, (uint_t*)xb, N * 128 / 4);
  WP wp;
  wp.p[0] = pre_w0;  wp.p[1] = arma_w0; wp.p[2] = arma_v0;
  wp.p[3] = sage_wl0; wp.p[4] = sage_wr0;
  wp.p[5] = pre_w1;  wp.p[6] = pre_w1 + 128 * 128;
  wp.p[7] = arma_w1; wp.p[8] = arma_v1;
  wp.p[9] = sage_wl1; wp.p[10] = sage_wr1;
  wtp_k<<<11, 256, 0, stream>>>(wp, wt);

  const int gB = (N + 127) / 128;
  const int gA = (N + 3) / 4;
  auto WT = [&](int i) { return wt + (size_t)i * 128 * 128; };

  // ---- cell 0 ----
  mgemm_k<0, 1><<<gB, 256, 0, stream>>>(xb, nullptr, WT(0), nullptr, pre_b0, hp, N);
  agg_k<<<gA, 256, 0, stream>>>((const uint_t*)hp, srow, smeta, offs, (uint_t*)bufA, (uint_t*)bufS, N);
  mgemm_k<1, 2><<<gB, 256, 0, stream>>>(bufA, hp, WT(1), WT(2), arma_b0, bufA, N);
  mgemm_k<2, 2><<<gB, 256, 0, stream>>>(bufS, hp, WT(3), WT(4), sage_bl0, bufS, N);
  // ---- cell 1 ----
  mgemm_k<0, 2><<<gB, 256, 0, stream>>>(bufA, bufS, WT(5), WT(6), pre_b1, hp, N);
  agg_k<<<gA, 256, 0, stream>>>((const uint_t*)hp, srow, smeta, offs, (uint_t*)bufA, (uint_t*)bufS, N);
  mgemm_k<1, 2><<<gB, 256, 0, stream>>>(bufA, hp, WT(7), WT(8), arma_b1, bufA, N);
  mgemm_k<2, 2><<<gB, 256, 0, stream>>>(bufS, hp, WT(9), WT(10), sage_bl1, bufS, N);
  // ---- classifier ----
  cls_k<<<(N + 15) / 16, 256, 0, stream>>>(bufA, bufS, cls_w, cls_b, (float*)d_out, N);
}

// Round 3
// 673.541 us; speedup vs baseline: 1.7438x; 1.2054x over previous
//
#include <hip/hip_runtime.h>
#include <hip/hip_bf16.h>

typedef __bf16 bf16x8 __attribute__((ext_vector_type(8)));
typedef float f32x4 __attribute__((ext_vector_type(4)));
typedef unsigned short ushort_t;
typedef unsigned int uint_t;

#if defined(__has_builtin)
#if __has_builtin(__builtin_amdgcn_global_load_lds)
#define HAS_GLL 1
#endif
#endif

// ---- bf16 helpers (storage = ushort) ----
__device__ inline float blo(uint_t v) { return __uint_as_float(v << 16); }
__device__ inline float bhi(uint_t v) { return __uint_as_float(v & 0xffff0000u); }
__device__ inline ushort_t f2b(float f) {  // RTNE
  uint_t u = __float_as_uint(f);
  uint_t r = (u + 0x7fffu + ((u >> 16) & 1u)) >> 16;
  return (ushort_t)r;
}
__device__ inline uint_t pk2(float a, float b) {
  return (uint_t)f2b(a) | ((uint_t)f2b(b) << 16);
}

// ---------------- precompute kernels ----------------

__global__ void degcnt_k(const int* __restrict__ col, const float* __restrict__ ew,
                         float* __restrict__ deg, int* __restrict__ cnti, int E) {
  int e = blockIdx.x * blockDim.x + threadIdx.x;
  if (e < E) {
    int c = col[e];
    atomicAdd(&deg[c], ew[e]);
    atomicAdd(&cnti[c], 1);
  }
}

__global__ void node_k(const float* __restrict__ deg, const int* __restrict__ cnti,
                       float* __restrict__ dinv, float* __restrict__ cinv, int n) {
  int i = blockIdx.x * blockDim.x + threadIdx.x;
  if (i < n) {
    float d = deg[i];
    dinv[i] = d > 0.f ? rsqrtf(d) : 0.f;
    cinv[i] = 1.0f / fmaxf((float)cnti[i], 1.f);
  }
}

__global__ void scan1_k(const int* __restrict__ cnti, int* __restrict__ bsum, int n) {
  __shared__ int sd[256];
  int t = threadIdx.x, b = blockIdx.x;
  int base = b * 1024 + t * 4;
  int s = 0;
#pragma unroll
  for (int j = 0; j < 4; ++j) { int i = base + j; if (i < n) s += cnti[i]; }
  sd[t] = s; __syncthreads();
  for (int off = 128; off > 0; off >>= 1) {
    if (t < off) sd[t] += sd[t + off];
    __syncthreads();
  }
  if (t == 0) bsum[b] = sd[0];
}

// parallel block-offset scan (B <= 256 fast path)
__global__ void scan2_k(const int* __restrict__ bsum, int* __restrict__ boff, int B) {
  __shared__ int sd[256];
  int t = threadIdx.x;
  if (B > 256) {
    if (t == 0) { int acc = 0; for (int b = 0; b < B; ++b) { boff[b] = acc; acc += bsum[b]; } }
    return;
  }
  int v = (t < B) ? bsum[t] : 0;
  int acc = v;
  sd[t] = v; __syncthreads();
  for (int off = 1; off < 256; off <<= 1) {
    int x = (t >= off) ? sd[t - off] : 0;
    __syncthreads();
    acc += x;
    sd[t] = acc;
    __syncthreads();
  }
  if (t < B) boff[t] = acc - v;
}

__global__ void scan3_k(const int* __restrict__ cnti, const int* __restrict__ boff,
                        int* __restrict__ offs, int* __restrict__ cursor, int n, int E) {
  __shared__ int sd[256];
  int t = threadIdx.x, b = blockIdx.x;
  int base = b * 1024 + t * 4;
  int v[4]; int s = 0;
#pragma unroll
  for (int j = 0; j < 4; ++j) { int i = base + j; v[j] = (i < n) ? cnti[i] : 0; s += v[j]; }
  sd[t] = s; __syncthreads();
  for (int off = 1; off < 256; off <<= 1) {
    int x = (t >= off) ? sd[t - off] : 0;
    __syncthreads();
    sd[t] += x;
    __syncthreads();
  }
  int excl = sd[t] - s + boff[b];
#pragma unroll
  for (int j = 0; j < 4; ++j) {
    int i = base + j;
    if (i < n) { offs[i] = excl; cursor[i] = excl; excl += v[j]; }
  }
  if (b == 0 && t == 0) offs[n] = E;
}

// meta = {sym-norm, ew/cnt[col]} packed per edge (sorted by col)
__global__ void fill_k(const int* __restrict__ row, const int* __restrict__ col,
                       const float* __restrict__ ew, const float* __restrict__ dinv,
                       const float* __restrict__ cinv, int* __restrict__ cursor,
                       int* __restrict__ srow, float2* __restrict__ smeta, int E) {
  int e = blockIdx.x * blockDim.x + threadIdx.x;
  if (e < E) {
    int r = row[e], c = col[e];
    float wgt = ew[e];
    int pos = atomicAdd(&cursor[c], 1);
    srow[pos] = r;
    smeta[pos] = make_float2(dinv[r] * wgt * dinv[c], wgt * cinv[c]);
  }
}

// ---------------- convert x to bf16 ----------------
__global__ void cvt_k(const float* __restrict__ in, uint_t* __restrict__ out, int n4) {
  int i = blockIdx.x * blockDim.x + threadIdx.x;
  if (i < n4) {
    float4 v = *(const float4*)&in[(size_t)i * 4];
    out[(size_t)i * 2]     = pk2(v.x, v.y);
    out[(size_t)i * 2 + 1] = pk2(v.z, v.w);
  }
}

// ---------------- weight transpose+convert: Wt[c][k] = bf16(W[k][c]) ----------------
struct WP { const float* p[11]; };
__global__ void wtp_k(WP wp, ushort_t* __restrict__ wt) {
  int b = blockIdx.x;
  const float* W = wp.p[b];
  ushort_t* T = wt + (size_t)b * 128 * 128;
  for (int i = 0; i < 64; ++i) {
    int lin = i * 256 + threadIdx.x;
    int k = lin >> 7, c = lin & 127;
    T[c * 128 + k] = f2b(W[lin]);
  }
}

// ---------------- aggregation: one wave per node, 8-wide MLP gather ----------------
__global__ __launch_bounds__(256) void agg_k(
    const uint_t* __restrict__ hp2, const int* __restrict__ srow,
    const float2* __restrict__ smeta, const int* __restrict__ offs,
    uint_t* __restrict__ outA, uint_t* __restrict__ outS, int n) {
  int wid = threadIdx.x >> 6;
  int lane = threadIdx.x & 63;
  int node = blockIdx.x * 4 + wid;
  if (node >= n) return;
  int s0 = offs[node], e0 = offs[node + 1];
  float a0 = 0.f, a1 = 0.f, m0 = 0.f, m1 = 0.f;
  for (int p = s0; p < e0; p += 8) {
    int idx[8]; float2 w[8]; uint_t v[8]; int r[8];
#pragma unroll
    for (int j = 0; j < 8; ++j) {
      bool ok = (p + j < e0);
      idx[j] = ok ? p + j : p;
    }
#pragma unroll
    for (int j = 0; j < 8; ++j) r[j] = srow[idx[j]];
#pragma unroll
    for (int j = 0; j < 8; ++j) v[j] = hp2[(size_t)r[j] * 64 + lane];
#pragma unroll
    for (int j = 0; j < 8; ++j) {
      bool ok = (p + j < e0);
      float2 ww = smeta[idx[j]];
      w[j] = ok ? ww : make_float2(0.f, 0.f);
    }
#pragma unroll
    for (int j = 0; j < 8; ++j) {
      float f0 = blo(v[j]), f1 = bhi(v[j]);
      a0 += w[j].x * f0; a1 += w[j].x * f1;
      m0 += w[j].y * f0; m1 += w[j].y * f1;
    }
  }
  outA[(size_t)node * 64 + lane] = pk2(a0, a1);
  outS[(size_t)node * 64 + lane] = pk2(m0, m1);
}

// ---------------- MFMA bf16 GEMM: out = act(A1@W1 [+ A2@W2] + bias) ----------------
// A*: (>=nrows_pad,128) bf16 row-major (workspace, padded). Wt*: (128,128) bf16 transposed.
// ACT: 0=none, 1=relu, 2=elu(leaky_relu(x,0.01))
__device__ inline int swz(int r, int k) { return (r * 128 + k) ^ ((r & 7) << 3); }

template <int ACT, int NSRC>
__global__ __launch_bounds__(256) void mgemm_k(
    const ushort_t* __restrict__ A1, const ushort_t* __restrict__ A2,
    const ushort_t* __restrict__ Wt1, const ushort_t* __restrict__ Wt2,
    const float* __restrict__ bias, ushort_t* __restrict__ out, int nrows) {
  __shared__ ushort_t As[128 * 128];
  __shared__ ushort_t Ws[128 * 128];
  int t = threadIdx.x;
  int lane = t & 63, wid = t >> 6;
  int wr = wid >> 1, wc = wid & 1;   // 2x2 wave grid, each wave 64x64
  int rowBase = blockIdx.x * 128;
  f32x4 acc[4][4] = {};

#pragma unroll
  for (int src = 0; src < NSRC; ++src) {
    const ushort_t* A = src ? A2 : A1;
    const ushort_t* Wt = src ? Wt2 : Wt1;
    if (src) __syncthreads();
#ifdef HAS_GLL
    {
      // DMA staging: linear LDS dest, inverse-swizzled global source (involution)
      int lr = lane >> 4;
      int lchunk = lane & 15;
#pragma unroll
      for (int i = 0; i < 8; ++i) {
        int r = wid * 32 + i * 4 + lr;                    // 0..127
        int csrc = (lchunk ^ (r & 7)) << 4;               // byte offset in row
        const char* gA = (const char*)A + (((size_t)(rowBase + r)) << 8) + csrc;
        const char* gW = (const char*)Wt + (((size_t)r) << 8) + csrc;
        char* lA = (char*)As + ((wid * 32 + i * 4) << 8); // wave-uniform base
        char* lW = (char*)Ws + ((wid * 32 + i * 4) << 8);
        __builtin_amdgcn_global_load_lds((const __attribute__((address_space(1))) void*)gA,
                                         (__attribute__((address_space(3))) void*)lA, 16, 0, 0);
        __builtin_amdgcn_global_load_lds((const __attribute__((address_space(1))) void*)gW,
                                         (__attribute__((address_space(3))) void*)lW, 16, 0, 0);
      }
      asm volatile("s_waitcnt vmcnt(0)" ::: "memory");
    }
#else
    {
#pragma unroll
      for (int i = 0; i < 8; ++i) {
        int f = t + i * 256;
        int r = f >> 4;
        int kq = (f & 15) * 8;
        *(uint4*)&As[swz(r, kq)] = *(const uint4*)&A[(size_t)(rowBase + r) * 128 + kq];
        *(uint4*)&Ws[swz(r, kq)] = *(const uint4*)&Wt[(size_t)r * 128 + kq];
      }
    }
#endif
    __syncthreads();
#pragma unroll
    for (int k = 0; k < 4; ++k) {
      bf16x8 af[4], bfr[4];
#pragma unroll
      for (int m = 0; m < 4; ++m)
        af[m] = *(const bf16x8*)&As[swz(wr * 64 + m * 16 + (lane & 15), k * 32 + (lane >> 4) * 8)];
#pragma unroll
      for (int nn = 0; nn < 4; ++nn)
        bfr[nn] = *(const bf16x8*)&Ws[swz(wc * 64 + nn * 16 + (lane & 15), k * 32 + (lane >> 4) * 8)];
#pragma unroll
      for (int m = 0; m < 4; ++m)
#pragma unroll
        for (int nn = 0; nn < 4; ++nn)
          acc[m][nn] = __builtin_amdgcn_mfma_f32_16x16x32_bf16(af[m], bfr[nn], acc[m][nn], 0, 0, 0);
    }
  }
  // epilogue: C/D layout col=lane&15, row=(lane>>4)*4+j
#pragma unroll
  for (int m = 0; m < 4; ++m) {
    int gr0 = rowBase + wr * 64 + m * 16 + (lane >> 4) * 4;
#pragma unroll
    for (int nn = 0; nn < 4; ++nn) {
      int gc = wc * 64 + nn * 16 + (lane & 15);
      float bv = bias[gc];
#pragma unroll
      for (int j = 0; j < 4; ++j) {
        int gr = gr0 + j;
        if (gr < nrows) {
          float v = acc[m][nn][j] + bv;
          if (ACT == 1) v = fmaxf(v, 0.f);
          if (ACT == 2) v = v > 0.f ? v : (__expf(0.01f * v) - 1.f);
          out[(size_t)gr * 128 + gc] = f2b(v);
        }
      }
    }
  }
}

// ---------------- classifier ----------------
__global__ __launch_bounds__(256) void cls_k(
    const ushort_t* __restrict__ h1, const ushort_t* __restrict__ h2,
    const float* __restrict__ W, const float* __restrict__ b,
    float* __restrict__ out, int n) {
  __shared__ float hs[16][260];
  __shared__ float Wl[4096];
  int t = threadIdx.x;
  int c = t & 15, nl = t >> 4;
  int n0 = blockIdx.x * 16;
#pragma unroll
  for (int i = 0; i < 4; ++i) {
    int idx = t + i * 256;  // 1024 float4 = 4096 floats
    *(float4*)&Wl[idx * 4] = *(const float4*)&W[idx * 4];
  }
#pragma unroll
  for (int i = 0; i < 2; ++i) {
    int f = t + i * 256;
    int node = f >> 5;
    int q = f & 31;
    int gn = n0 + node;
    uint4 v = make_uint4(0, 0, 0, 0);
    if (gn < n)
      v = (q < 16) ? *(const uint4*)&h1[(size_t)gn * 128 + q * 8]
                   : *(const uint4*)&h2[(size_t)gn * 128 + (q - 16) * 8];
    int base = q * 8;
    uint_t u[4] = {v.x, v.y, v.z, v.w};
#pragma unroll
    for (int j = 0; j < 4; ++j) {
      hs[node][base + 2 * j]     = blo(u[j]);
      hs[node][base + 2 * j + 1] = bhi(u[j]);
    }
  }
  __syncthreads();
  float acc = b[c];
#pragma unroll 8
  for (int k = 0; k < 256; ++k) acc += hs[nl][k] * Wl[k * 16 + c];
  float mx = acc;
  for (int d = 1; d < 16; d <<= 1) mx = fmaxf(mx, __shfl_xor(mx, d));
  float ex = __expf(acc - mx);
  float sum = ex;
  for (int d = 1; d < 16; d <<= 1) sum += __shfl_xor(sum, d);
  float r = (acc - mx) - logf(sum);
  int gn = n0 + nl;
  if (gn < n) out[gn * 16 + c] = r;
}

// ---------------- launch ----------------

extern "C" void kernel_launch(void* const* d_in, const int* in_sizes, int n_in,
                              void* d_out, int out_size, void* d_ws, size_t ws_size,
                              hipStream_t stream) {
  const float* x        = (const float*)d_in[0];
  const int*   eidx     = (const int*)d_in[1];
  const float* ew       = (const float*)d_in[2];
  const float* pre_w0   = (const float*)d_in[3];
  const float* pre_b0   = (const float*)d_in[4];
  const float* arma_w0  = (const float*)d_in[5];
  const float* arma_v0  = (const float*)d_in[6];
  const float* arma_b0  = (const float*)d_in[7];
  const float* sage_wl0 = (const float*)d_in[8];
  const float* sage_bl0 = (const float*)d_in[9];
  const float* sage_wr0 = (const float*)d_in[10];
  const float* pre_w1   = (const float*)d_in[11];
  const float* pre_b1   = (const float*)d_in[12];
  const float* arma_w1  = (const float*)d_in[13];
  const float* arma_v1  = (const float*)d_in[14];
  const float* arma_b1  = (const float*)d_in[15];
  const float* sage_wl1 = (const float*)d_in[16];
  const float* sage_bl1 = (const float*)d_in[17];
  const float* sage_wr1 = (const float*)d_in[18];
  const float* cls_w    = (const float*)d_in[19];
  const float* cls_b    = (const float*)d_in[20];

  const int N = in_sizes[0] / 128;
  const int E = in_sizes[2];
  const int N_pad = ((N + 127) / 128) * 128;
  const int* row = eidx;
  const int* col = eidx + E;

  char* p = (char*)d_ws;
  auto carve = [&](size_t bytes) { char* q = p; p += (bytes + 255) & ~(size_t)255; return q; };
  ushort_t* hp    = (ushort_t*)carve((size_t)N_pad * 128 * 2);
  ushort_t* bufA  = (ushort_t*)carve((size_t)N_pad * 128 * 2);
  ushort_t* bufS  = (ushort_t*)carve((size_t)N_pad * 128 * 2);
  ushort_t* xb    = (ushort_t*)carve((size_t)N_pad * 128 * 2);
  ushort_t* wt    = (ushort_t*)carve((size_t)11 * 128 * 128 * 2);
  int*    srow  = (int*)carve((size_t)E * 4);
  float2* smeta = (float2*)carve((size_t)E * 8);
  float*  deg   = (float*)carve((size_t)N * 4);
  float*  dinv  = (float*)carve((size_t)N * 4);
  float*  cinv  = (float*)carve((size_t)N * 4);
  int*    cnti  = (int*)carve((size_t)N * 4);
  int*    offs  = (int*)carve((size_t)(N + 1) * 4);
  int*    cursor= (int*)carve((size_t)N * 4);
  const int B   = (N + 1023) / 1024;
  int*    bsum  = (int*)carve((size_t)B * 4);
  int*    boff  = (int*)carve((size_t)B * 4);

  hipMemsetAsync(deg, 0, (size_t)N * 4, stream);
  hipMemsetAsync(cnti, 0, (size_t)N * 4, stream);

  degcnt_k<<<(E + 255) / 256, 256, 0, stream>>>(col, ew, deg, cnti, E);
  node_k<<<(N + 255) / 256, 256, 0, stream>>>(deg, cnti, dinv, cinv, N);
  scan1_k<<<B, 256, 0, stream>>>(cnti, bsum, N);
  scan2_k<<<1, 256, 0, stream>>>(bsum, boff, B);
  scan3_k<<<B, 256, 0, stream>>>(cnti, boff, offs, cursor, N, E);
  fill_k<<<(E + 255) / 256, 256, 0, stream>>>(row, col, ew, dinv, cinv, cursor, srow, smeta, E);

  cvt_k<<<(N * 128 / 4 + 255) / 256, 256, 0, stream>>>(x, (uint_t*)xb, N * 128 / 4);
  WP wp;
  wp.p[0] = pre_w0;  wp.p[1] = arma_w0; wp.p[2] = arma_v0;
  wp.p[3] = sage_wl0; wp.p[4] = sage_wr0;
  wp.p[5] = pre_w1;  wp.p[6] = pre_w1 + 128 * 128;
  wp.p[7] = arma_w1; wp.p[8] = arma_v1;
  wp.p[9] = sage_wl1; wp.p[10] = sage_wr1;
  wtp_k<<<11, 256, 0, stream>>>(wp, wt);

  const int gB = (N + 127) / 128;
  const int gA = (N + 3) / 4;
  auto WT = [&](int i) { return wt + (size_t)i * 128 * 128; };

  // ---- cell 0 ----
  mgemm_k<0, 1><<<gB, 256, 0, stream>>>(xb, nullptr, WT(0), nullptr, pre_b0, hp, N);
  agg_k<<<gA, 256, 0, stream>>>((const uint_t*)hp, srow, smeta, offs, (uint_t*)bufA, (uint_t*)bufS, N);
  mgemm_k<1, 2><<<gB, 256, 0, stream>>>(bufA, hp, WT(1), WT(2), arma_b0, bufA, N);
  mgemm_k<2, 2><<<gB, 256, 0, stream>>>(bufS, hp, WT(3), WT(4), sage_bl0, bufS, N);
  // ---- cell 1 ----
  mgemm_k<0, 2><<<gB, 256, 0, stream>>>(bufA, bufS, WT(5), WT(6), pre_b1, hp, N);
  agg_k<<<gA, 256, 0, stream>>>((const uint_t*)hp, srow, smeta, offs, (uint_t*)bufA, (uint_t*)bufS, N);
  mgemm_k<1, 2><<<gB, 256, 0, stream>>>(bufA, hp, WT(7), WT(8), arma_b1, bufA, N);
  mgemm_k<2, 2><<<gB, 256, 0, stream>>>(bufS, hp, WT(9), WT(10), sage_bl1, bufS, N);
  // ---- classifier ----
  cls_k<<<(N + 15) / 16, 256, 0, stream>>>(bufA, bufS, cls_w, cls_b, (float*)d_out, N);
}

// Round 4
// 621.287 us; speedup vs baseline: 1.8905x; 1.0841x over previous
//
#include <hip/hip_runtime.h>
#include <hip/hip_bf16.h>

typedef __bf16 bf16x8 __attribute__((ext_vector_type(8)));
typedef float f32x4 __attribute__((ext_vector_type(4)));
typedef unsigned short ushort_t;
typedef unsigned int uint_t;

#if defined(__has_builtin)
#if __has_builtin(__builtin_amdgcn_global_load_lds)
#define HAS_GLL 1
#endif
#endif

// ---- bf16 helpers (storage = ushort) ----
__device__ inline float blo(uint_t v) { return __uint_as_float(v << 16); }
__device__ inline float bhi(uint_t v) { return __uint_as_float(v & 0xffff0000u); }
__device__ inline ushort_t f2b(float f) {  // RTNE
  uint_t u = __float_as_uint(f);
  uint_t r = (u + 0x7fffu + ((u >> 16) & 1u)) >> 16;
  return (ushort_t)r;
}
__device__ inline uint_t pk2(float a, float b) {
  return (uint_t)f2b(a) | ((uint_t)f2b(b) << 16);
}

// ---------------- precompute kernels ----------------

// histogram of destinations: 1 int atomic per edge
__global__ void hist_k(const int* __restrict__ col, int* __restrict__ cnti, int E) {
  int e = blockIdx.x * blockDim.x + threadIdx.x;
  if (e < E) atomicAdd(&cnti[col[e]], 1);
}

__global__ void scan1_k(const int* __restrict__ cnti, int* __restrict__ bsum, int n) {
  __shared__ int sd[256];
  int t = threadIdx.x, b = blockIdx.x;
  int base = b * 1024 + t * 4;
  int s = 0;
#pragma unroll
  for (int j = 0; j < 4; ++j) { int i = base + j; if (i < n) s += cnti[i]; }
  sd[t] = s; __syncthreads();
  for (int off = 128; off > 0; off >>= 1) {
    if (t < off) sd[t] += sd[t + off];
    __syncthreads();
  }
  if (t == 0) bsum[b] = sd[0];
}

// parallel block-offset scan (B <= 256 fast path)
__global__ void scan2_k(const int* __restrict__ bsum, int* __restrict__ boff, int B) {
  __shared__ int sd[256];
  int t = threadIdx.x;
  if (B > 256) {
    if (t == 0) { int acc = 0; for (int b = 0; b < B; ++b) { boff[b] = acc; acc += bsum[b]; } }
    return;
  }
  int v = (t < B) ? bsum[t] : 0;
  int acc = v;
  sd[t] = v; __syncthreads();
  for (int off = 1; off < 256; off <<= 1) {
    int x = (t >= off) ? sd[t - off] : 0;
    __syncthreads();
    acc += x;
    sd[t] = acc;
    __syncthreads();
  }
  if (t < B) boff[t] = acc - v;
}

__global__ void scan3_k(const int* __restrict__ cnti, const int* __restrict__ boff,
                        int* __restrict__ offs, int* __restrict__ cursor, int n, int E) {
  __shared__ int sd[256];
  int t = threadIdx.x, b = blockIdx.x;
  int base = b * 1024 + t * 4;
  int v[4]; int s = 0;
#pragma unroll
  for (int j = 0; j < 4; ++j) { int i = base + j; v[j] = (i < n) ? cnti[i] : 0; s += v[j]; }
  sd[t] = s; __syncthreads();
  for (int off = 1; off < 256; off <<= 1) {
    int x = (t >= off) ? sd[t - off] : 0;
    __syncthreads();
    sd[t] += x;
    __syncthreads();
  }
  int excl = sd[t] - s + boff[b];
#pragma unroll
  for (int j = 0; j < 4; ++j) {
    int i = base + j;
    if (i < n) { offs[i] = excl; cursor[i] = excl; excl += v[j]; }
  }
  if (b == 0 && t == 0) offs[n] = E;
}

// CSR fill: 1 atomic + one packed 8B store per edge
__global__ void fill2_k(const int* __restrict__ row, const int* __restrict__ col,
                        const float* __restrict__ ew, int* __restrict__ cursor,
                        uint2* __restrict__ sedge, int E) {
  int e = blockIdx.x * blockDim.x + threadIdx.x;
  if (e < E) {
    int c = col[e];
    int pos = atomicAdd(&cursor[c], 1);
    uint2 v;
    v.x = (uint_t)row[e];
    v.y = __float_as_uint(ew[e]);
    sedge[pos] = v;
  }
}

// per-node: deg = contiguous segment-sum of ew; cnt from offs
__global__ void node2_k(const uint2* __restrict__ sedge, const int* __restrict__ offs,
                        float* __restrict__ dinv, float* __restrict__ cinv, int n) {
  int i = blockIdx.x * blockDim.x + threadIdx.x;
  if (i < n) {
    int s0 = offs[i], e0 = offs[i + 1];
    float deg = 0.f;
    for (int p = s0; p < e0; ++p) deg += __uint_as_float(sedge[p].y);
    dinv[i] = deg > 0.f ? rsqrtf(deg) : 0.f;
    cinv[i] = 1.0f / fmaxf((float)(e0 - s0), 1.f);
  }
}

// ---------------- convert x to bf16 ----------------
__global__ void cvt_k(const float* __restrict__ in, uint_t* __restrict__ out, int n4) {
  int i = blockIdx.x * blockDim.x + threadIdx.x;
  if (i < n4) {
    float4 v = *(const float4*)&in[(size_t)i * 4];
    out[(size_t)i * 2]     = pk2(v.x, v.y);
    out[(size_t)i * 2 + 1] = pk2(v.z, v.w);
  }
}

// ---------------- weight transpose+convert: Wt[c][k] = bf16(W[k][c]) ----------------
struct WP { const float* p[11]; };
__global__ void wtp_k(WP wp, ushort_t* __restrict__ wt) {
  int b = blockIdx.x;
  const float* W = wp.p[b];
  ushort_t* T = wt + (size_t)b * 128 * 128;
  for (int i = 0; i < 64; ++i) {
    int lin = i * 256 + threadIdx.x;
    int k = lin >> 7, c = lin & 127;
    T[c * 128 + k] = f2b(W[lin]);
  }
}

// ---------------- aggregation: one wave per node, 2 edges/step, 8B/lane ----------------
// outA[node] = dinv[node] * sum_e dinv[r_e]*ew_e*h[r_e]
// outS[node] = cinv[node] * sum_e ew_e*h[r_e]
__global__ __launch_bounds__(256) void agg_k(
    const uint_t* __restrict__ hp2, const uint2* __restrict__ sedge,
    const float* __restrict__ dinv, const float* __restrict__ cinv,
    const int* __restrict__ offs,
    uint_t* __restrict__ outA, uint_t* __restrict__ outS, int n) {
  int wid = threadIdx.x >> 6;
  int lane = threadIdx.x & 63;
  int half = lane >> 5, li = lane & 31;
  int node = blockIdx.x * 4 + wid;
  if (node >= n) return;
  int s0 = offs[node], e0 = offs[node + 1];
  float a0 = 0.f, a1 = 0.f, a2 = 0.f, a3 = 0.f;
  float m0 = 0.f, m1 = 0.f, m2 = 0.f, m3 = 0.f;
  for (int p = s0; p < e0; p += 16) {
#pragma unroll
    for (int j = 0; j < 8; ++j) {
      int k = p + j * 2 + half;
      bool ok = (k < e0);
      int kk = ok ? k : s0;
      uint2 ed = sedge[kk];
      float ew = ok ? __uint_as_float(ed.y) : 0.f;
      float dr = dinv[ed.x];
      float wA = dr * ew;
      uint2 v = *(const uint2*)&hp2[(size_t)ed.x * 64 + li * 2];
      float f0 = blo(v.x), f1 = bhi(v.x), f2 = blo(v.y), f3 = bhi(v.y);
      a0 += wA * f0; a1 += wA * f1; a2 += wA * f2; a3 += wA * f3;
      m0 += ew * f0; m1 += ew * f1; m2 += ew * f2; m3 += ew * f3;
    }
  }
  a0 += __shfl_xor(a0, 32); a1 += __shfl_xor(a1, 32);
  a2 += __shfl_xor(a2, 32); a3 += __shfl_xor(a3, 32);
  m0 += __shfl_xor(m0, 32); m1 += __shfl_xor(m1, 32);
  m2 += __shfl_xor(m2, 32); m3 += __shfl_xor(m3, 32);
  if (half == 0) {
    float dn = dinv[node];
    uint2 o;
    o.x = pk2(dn * a0, dn * a1);
    o.y = pk2(dn * a2, dn * a3);
    *(uint2*)&outA[(size_t)node * 64 + li * 2] = o;
  } else {
    float cn = cinv[node];
    uint2 o;
    o.x = pk2(cn * m0, cn * m1);
    o.y = pk2(cn * m2, cn * m3);
    *(uint2*)&outS[(size_t)node * 64 + li * 2] = o;
  }
}

// ---------------- MFMA bf16 GEMM: out = act(A1@W1 [+ A2@W2] + bias) ----------------
__device__ inline int swz(int r, int k) { return (r * 128 + k) ^ ((r & 7) << 3); }

template <int ACT, int NSRC>
__global__ __launch_bounds__(256) void mgemm_k(
    const ushort_t* __restrict__ A1, const ushort_t* __restrict__ A2,
    const ushort_t* __restrict__ Wt1, const ushort_t* __restrict__ Wt2,
    const float* __restrict__ bias, ushort_t* __restrict__ out, int nrows) {
  __shared__ ushort_t As[128 * 128];
  __shared__ ushort_t Ws[128 * 128];
  int t = threadIdx.x;
  int lane = t & 63, wid = t >> 6;
  int wr = wid >> 1, wc = wid & 1;   // 2x2 wave grid, each wave 64x64
  int rowBase = blockIdx.x * 128;
  f32x4 acc[4][4] = {};

#pragma unroll
  for (int src = 0; src < NSRC; ++src) {
    const ushort_t* A = src ? A2 : A1;
    const ushort_t* Wt = src ? Wt2 : Wt1;
    if (src) __syncthreads();
#ifdef HAS_GLL
    {
      int lr = lane >> 4;
      int lchunk = lane & 15;
#pragma unroll
      for (int i = 0; i < 8; ++i) {
        int r = wid * 32 + i * 4 + lr;
        int csrc = (lchunk ^ (r & 7)) << 4;
        const char* gA = (const char*)A + (((size_t)(rowBase + r)) << 8) + csrc;
        const char* gW = (const char*)Wt + (((size_t)r) << 8) + csrc;
        char* lA = (char*)As + ((wid * 32 + i * 4) << 8);
        char* lW = (char*)Ws + ((wid * 32 + i * 4) << 8);
        __builtin_amdgcn_global_load_lds((const __attribute__((address_space(1))) void*)gA,
                                         (__attribute__((address_space(3))) void*)lA, 16, 0, 0);
        __builtin_amdgcn_global_load_lds((const __attribute__((address_space(1))) void*)gW,
                                         (__attribute__((address_space(3))) void*)lW, 16, 0, 0);
      }
      asm volatile("s_waitcnt vmcnt(0)" ::: "memory");
    }
#else
    {
#pragma unroll
      for (int i = 0; i < 8; ++i) {
        int f = t + i * 256;
        int r = f >> 4;
        int kq = (f & 15) * 8;
        *(uint4*)&As[swz(r, kq)] = *(const uint4*)&A[(size_t)(rowBase + r) * 128 + kq];
        *(uint4*)&Ws[swz(r, kq)] = *(const uint4*)&Wt[(size_t)r * 128 + kq];
      }
    }
#endif
    __syncthreads();
#pragma unroll
    for (int k = 0; k < 4; ++k) {
      bf16x8 af[4], bfr[4];
#pragma unroll
      for (int m = 0; m < 4; ++m)
        af[m] = *(const bf16x8*)&As[swz(wr * 64 + m * 16 + (lane & 15), k * 32 + (lane >> 4) * 8)];
#pragma unroll
      for (int nn = 0; nn < 4; ++nn)
        bfr[nn] = *(const bf16x8*)&Ws[swz(wc * 64 + nn * 16 + (lane & 15), k * 32 + (lane >> 4) * 8)];
#pragma unroll
      for (int m = 0; m < 4; ++m)
#pragma unroll
        for (int nn = 0; nn < 4; ++nn)
          acc[m][nn] = __builtin_amdgcn_mfma_f32_16x16x32_bf16(af[m], bfr[nn], acc[m][nn], 0, 0, 0);
    }
  }
#pragma unroll
  for (int m = 0; m < 4; ++m) {
    int gr0 = rowBase + wr * 64 + m * 16 + (lane >> 4) * 4;
#pragma unroll
    for (int nn = 0; nn < 4; ++nn) {
      int gc = wc * 64 + nn * 16 + (lane & 15);
      float bv = bias[gc];
#pragma unroll
      for (int j = 0; j < 4; ++j) {
        int gr = gr0 + j;
        if (gr < nrows) {
          float v = acc[m][nn][j] + bv;
          if (ACT == 1) v = fmaxf(v, 0.f);
          if (ACT == 2) v = v > 0.f ? v : (__expf(0.01f * v) - 1.f);
          out[(size_t)gr * 128 + gc] = f2b(v);
        }
      }
    }
  }
}

// ---------------- classifier ----------------
__global__ __launch_bounds__(256) void cls_k(
    const ushort_t* __restrict__ h1, const ushort_t* __restrict__ h2,
    const float* __restrict__ W, const float* __restrict__ b,
    float* __restrict__ out, int n) {
  __shared__ float hs[16][260];
  __shared__ float Wl[4096];
  int t = threadIdx.x;
  int c = t & 15, nl = t >> 4;
  int n0 = blockIdx.x * 16;
#pragma unroll
  for (int i = 0; i < 4; ++i) {
    int idx = t + i * 256;
    *(float4*)&Wl[idx * 4] = *(const float4*)&W[idx * 4];
  }
#pragma unroll
  for (int i = 0; i < 2; ++i) {
    int f = t + i * 256;
    int node = f >> 5;
    int q = f & 31;
    int gn = n0 + node;
    uint4 v = make_uint4(0, 0, 0, 0);
    if (gn < n)
      v = (q < 16) ? *(const uint4*)&h1[(size_t)gn * 128 + q * 8]
                   : *(const uint4*)&h2[(size_t)gn * 128 + (q - 16) * 8];
    int base = q * 8;
    uint_t u[4] = {v.x, v.y, v.z, v.w};
#pragma unroll
    for (int j = 0; j < 4; ++j) {
      hs[node][base + 2 * j]     = blo(u[j]);
      hs[node][base + 2 * j + 1] = bhi(u[j]);
    }
  }
  __syncthreads();
  float acc = b[c];
#pragma unroll 8
  for (int k = 0; k < 256; ++k) acc += hs[nl][k] * Wl[k * 16 + c];
  float mx = acc;
  for (int d = 1; d < 16; d <<= 1) mx = fmaxf(mx, __shfl_xor(mx, d));
  float ex = __expf(acc - mx);
  float sum = ex;
  for (int d = 1; d < 16; d <<= 1) sum += __shfl_xor(sum, d);
  float r = (acc - mx) - logf(sum);
  int gn = n0 + nl;
  if (gn < n) out[gn * 16 + c] = r;
}

// ---------------- launch ----------------

extern "C" void kernel_launch(void* const* d_in, const int* in_sizes, int n_in,
                              void* d_out, int out_size, void* d_ws, size_t ws_size,
                              hipStream_t stream) {
  const float* x        = (const float*)d_in[0];
  const int*   eidx     = (const int*)d_in[1];
  const float* ew       = (const float*)d_in[2];
  const float* pre_w0   = (const float*)d_in[3];
  const float* pre_b0   = (const float*)d_in[4];
  const float* arma_w0  = (const float*)d_in[5];
  const float* arma_v0  = (const float*)d_in[6];
  const float* arma_b0  = (const float*)d_in[7];
  const float* sage_wl0 = (const float*)d_in[8];
  const float* sage_bl0 = (const float*)d_in[9];
  const float* sage_wr0 = (const float*)d_in[10];
  const float* pre_w1   = (const float*)d_in[11];
  const float* pre_b1   = (const float*)d_in[12];
  const float* arma_w1  = (const float*)d_in[13];
  const float* arma_v1  = (const float*)d_in[14];
  const float* arma_b1  = (const float*)d_in[15];
  const float* sage_wl1 = (const float*)d_in[16];
  const float* sage_bl1 = (const float*)d_in[17];
  const float* sage_wr1 = (const float*)d_in[18];
  const float* cls_w    = (const float*)d_in[19];
  const float* cls_b    = (const float*)d_in[20];

  const int N = in_sizes[0] / 128;
  const int E = in_sizes[2];
  const int N_pad = ((N + 127) / 128) * 128;
  const int* row = eidx;
  const int* col = eidx + E;

  char* p = (char*)d_ws;
  auto carve = [&](size_t bytes) { char* q = p; p += (bytes + 255) & ~(size_t)255; return q; };
  ushort_t* hp    = (ushort_t*)carve((size_t)N_pad * 128 * 2);
  ushort_t* bufA  = (ushort_t*)carve((size_t)N_pad * 128 * 2);
  ushort_t* bufS  = (ushort_t*)carve((size_t)N_pad * 128 * 2);
  ushort_t* xb    = (ushort_t*)carve((size_t)N_pad * 128 * 2);
  ushort_t* wt    = (ushort_t*)carve((size_t)11 * 128 * 128 * 2);
  uint2*  sedge = (uint2*)carve((size_t)E * 8);
  float*  dinv  = (float*)carve((size_t)N * 4);
  float*  cinv  = (float*)carve((size_t)N * 4);
  int*    cnti  = (int*)carve((size_t)N * 4);
  int*    offs  = (int*)carve((size_t)(N + 1) * 4);
  int*    cursor= (int*)carve((size_t)N * 4);
  const int B   = (N + 1023) / 1024;
  int*    bsum  = (int*)carve((size_t)B * 4);
  int*    boff  = (int*)carve((size_t)B * 4);

  hipMemsetAsync(cnti, 0, (size_t)N * 4, stream);

  hist_k<<<(E + 255) / 256, 256, 0, stream>>>(col, cnti, E);
  scan1_k<<<B, 256, 0, stream>>>(cnti, bsum, N);
  scan2_k<<<1, 256, 0, stream>>>(bsum, boff, B);
  scan3_k<<<B, 256, 0, stream>>>(cnti, boff, offs, cursor, N, E);
  fill2_k<<<(E + 255) / 256, 256, 0, stream>>>(row, col, ew, cursor, sedge, E);
  node2_k<<<(N + 255) / 256, 256, 0, stream>>>(sedge, offs, dinv, cinv, N);

  cvt_k<<<(N * 128 / 4 + 255) / 256, 256, 0, stream>>>(x, (uint_t*)xb, N * 128 / 4);
  WP wp;
  wp.p[0] = pre_w0;  wp.p[1] = arma_w0; wp.p[2] = arma_v0;
  wp.p[3] = sage_wl0; wp.p[4] = sage_wr0;
  wp.p[5] = pre_w1;  wp.p[6] = pre_w1 + 128 * 128;
  wp.p[7] = arma_w1; wp.p[8] = arma_v1;
  wp.p[9] = sage_wl1; wp.p[10] = sage_wr1;
  wtp_k<<<11, 256, 0, stream>>>(wp, wt);

  const int gB = (N + 127) / 128;
  const int gA = (N + 3) / 4;
  auto WT = [&](int i) { return wt + (size_t)i * 128 * 128; };

  // ---- cell 0 ----
  mgemm_k<0, 1><<<gB, 256, 0, stream>>>(xb, nullptr, WT(0), nullptr, pre_b0, hp, N);
  agg_k<<<gA, 256, 0, stream>>>((const uint_t*)hp, sedge, dinv, cinv, offs, (uint_t*)bufA, (uint_t*)bufS, N);
  mgemm_k<1, 2><<<gB, 256, 0, stream>>>(bufA, hp, WT(1), WT(2), arma_b0, bufA, N);
  mgemm_k<2, 2><<<gB, 256, 0, stream>>>(bufS, hp, WT(3), WT(4), sage_bl0, bufS, N);
  // ---- cell 1 ----
  mgemm_k<0, 2><<<gB, 256, 0, stream>>>(bufA, bufS, WT(5), WT(6), pre_b1, hp, N);
  agg_k<<<gA, 256, 0, stream>>>((const uint_t*)hp, sedge, dinv, cinv, offs, (uint_t*)bufA, (uint_t*)bufS, N);
  mgemm_k<1, 2><<<gB, 256, 0, stream>>>(bufA, hp, WT(7), WT(8), arma_b1, bufA, N);
  mgemm_k<2, 2><<<gB, 256, 0, stream>>>(bufS, hp, WT(9), WT(10), sage_bl1, bufS, N);
  // ---- classifier ----
  cls_k<<<(N + 15) / 16, 256, 0, stream>>>(bufA, bufS, cls_w, cls_b, (float*)d_out, N);
}

// Round 5
// 484.119 us; speedup vs baseline: 2.4261x; 1.2833x over previous
//
#include <hip/hip_runtime.h>
#include <hip/hip_bf16.h>

typedef __bf16 bf16x8 __attribute__((ext_vector_type(8)));
typedef float f32x4 __attribute__((ext_vector_type(4)));
typedef unsigned short ushort_t;
typedef unsigned int uint_t;

#if defined(__has_builtin)
#if __has_builtin(__builtin_amdgcn_global_load_lds)
#define HAS_GLL 1
#endif
#endif

// ---- bf16 helpers (storage = ushort) ----
__device__ inline float blo(uint_t v) { return __uint_as_float(v << 16); }
__device__ inline float bhi(uint_t v) { return __uint_as_float(v & 0xffff0000u); }
__device__ inline ushort_t f2b(float f) {  // RTNE
  uint_t u = __float_as_uint(f);
  uint_t r = (u + 0x7fffu + ((u >> 16) & 1u)) >> 16;
  return (ushort_t)r;
}
__device__ inline uint_t pk2(float a, float b) {
  return (uint_t)f2b(a) | ((uint_t)f2b(b) << 16);
}

// ================= CSR build via 2-pass bucket sort =================
// bucket = col >> 9 (512 nodes per bucket). NB <= 256 (N <= 131072).

// pass 0: bucket histogram (LDS hist, 1 global atomic per bucket per block)
__global__ __launch_bounds__(256) void bcount_k(const int* __restrict__ col,
                                                int* __restrict__ bcnt, int E, int NB) {
  __shared__ int h[256];
  int t = threadIdx.x;
  h[t] = 0;
  __syncthreads();
  int e0 = blockIdx.x * 8192;
#pragma unroll
  for (int j = 0; j < 32; ++j) {
    int e = e0 + j * 256 + t;
    if (e < E) atomicAdd(&h[col[e] >> 9], 1);
  }
  __syncthreads();
  if (t < NB && h[t] > 0) atomicAdd(&bcnt[t], h[t]);
}

// pass 0b: scan bucket sizes
__global__ __launch_bounds__(256) void bscan_k(const int* __restrict__ bcnt,
                                               int* __restrict__ bbase, int* __restrict__ cursor,
                                               int* __restrict__ offs, int NB, int N, int E) {
  __shared__ int sd[256];
  int t = threadIdx.x;
  int v = (t < NB) ? bcnt[t] : 0;
  int acc = v;
  sd[t] = v; __syncthreads();
  for (int off = 1; off < 256; off <<= 1) {
    int x = (t >= off) ? sd[t - off] : 0;
    __syncthreads();
    acc += x; sd[t] = acc;
    __syncthreads();
  }
  if (t < NB) { bbase[t] = acc - v; cursor[t] = acc - v; }
  if (t == 0) { bbase[NB] = E; offs[N] = E; }
}

// pass 1: scatter edges into bucket-contiguous regions (LDS-staged, coalesced runs)
__global__ __launch_bounds__(256) void bscatter_k(
    const int* __restrict__ row, const int* __restrict__ col, const float* __restrict__ ew,
    int* __restrict__ cursor, uint2* __restrict__ eout, int E, int NB) {
  __shared__ int h[256];
  __shared__ int lofs[256];
  __shared__ int lcur[256];
  __shared__ int gbase[256];
  __shared__ uint2 stage[8192];
  __shared__ int addr[8192];
  int t = threadIdx.x;
  int e0 = blockIdx.x * 8192;
  int cnt = min(8192, E - e0);
  h[t] = 0;
  __syncthreads();
#pragma unroll
  for (int j = 0; j < 32; ++j) {
    int e = e0 + j * 256 + t;
    if (e < E) atomicAdd(&h[col[e] >> 9], 1);
  }
  __syncthreads();
  int s = h[t];
  int acc = s;
  lofs[t] = s; __syncthreads();
  for (int off = 1; off < 256; off <<= 1) {
    int x = (t >= off) ? lofs[t - off] : 0;
    __syncthreads();
    acc += x; lofs[t] = acc;
    __syncthreads();
  }
  int excl = acc - s;
  if (t < NB && s > 0) gbase[t] = atomicAdd(&cursor[t], s);
  __syncthreads();
  lofs[t] = excl;
  lcur[t] = excl;
  __syncthreads();
#pragma unroll
  for (int j = 0; j < 32; ++j) {
    int e = e0 + j * 256 + t;
    if (e < E) {
      int c = col[e];
      int bk = c >> 9;
      int p = atomicAdd(&lcur[bk], 1);
      uint2 v;
      v.x = ((uint_t)(c & 511) << 17) | (uint_t)row[e];
      v.y = __float_as_uint(ew[e]);
      stage[p] = v;
      addr[p] = gbase[bk] + (p - lofs[bk]);
    }
  }
  __syncthreads();
  for (int i = t; i < cnt; i += 256) eout[addr[i]] = stage[i];
}

// pass 2: per-bucket node sort + node stats (deg, cnt) + CSR offsets
__global__ __launch_bounds__(256) void bsort_k(
    const uint2* __restrict__ ein, const int* __restrict__ bbase,
    int* __restrict__ offs, float* __restrict__ dinv, float* __restrict__ cinv,
    uint2* __restrict__ eout, int N) {
  __shared__ int h[512];
  __shared__ int lofs[512];
  __shared__ int lcur[512];
  __shared__ float degs[512];
  __shared__ int sd[256];
  __shared__ uint2 stage[14336];  // 112KB; mean bucket = 8192, +68 sigma
  int t = threadIdx.x, b = blockIdx.x;
  int base = bbase[b], end = bbase[b + 1];
  int cnt = end - base;
  int node0 = b << 9;
  h[t] = 0; h[t + 256] = 0;
  degs[t] = 0.f; degs[t + 256] = 0.f;
  __syncthreads();
  for (int i = t; i < cnt; i += 256) {
    uint2 v = ein[base + i];
    int lc = v.x >> 17;
    atomicAdd(&h[lc], 1);
    atomicAdd(&degs[lc], __uint_as_float(v.y));
  }
  __syncthreads();
  // pair-scan 512 with 256 threads
  int s = h[2 * t] + h[2 * t + 1];
  int acc = s;
  sd[t] = s; __syncthreads();
  for (int off = 1; off < 256; off <<= 1) {
    int x = (t >= off) ? sd[t - off] : 0;
    __syncthreads();
    acc += x; sd[t] = acc;
    __syncthreads();
  }
  int excl = acc - s;
  lofs[2 * t] = excl;
  lofs[2 * t + 1] = excl + h[2 * t];
  lcur[2 * t] = excl;
  lcur[2 * t + 1] = excl + h[2 * t];
  __syncthreads();
  for (int j = t; j < 512; j += 256) {
    int node = node0 + j;
    if (node < N) {
      offs[node] = base + lofs[j];
      float d = degs[j];
      dinv[node] = d > 0.f ? rsqrtf(d) : 0.f;
      cinv[node] = 1.0f / fmaxf((float)h[j], 1.f);
    }
  }
  for (int i = t; i < cnt; i += 256) {
    uint2 v = ein[base + i];
    int lc = v.x >> 17;
    int p = atomicAdd(&lcur[lc], 1);
    uint2 o;
    o.x = v.x & 0x1FFFF;
    o.y = v.y;
    stage[p] = o;
  }
  __syncthreads();
  for (int i = t; i < cnt; i += 256) eout[base + i] = stage[i];
}

// ---------------- convert x to bf16 ----------------
__global__ void cvt_k(const float* __restrict__ in, uint_t* __restrict__ out, int n4) {
  int i = blockIdx.x * blockDim.x + threadIdx.x;
  if (i < n4) {
    float4 v = *(const float4*)&in[(size_t)i * 4];
    out[(size_t)i * 2]     = pk2(v.x, v.y);
    out[(size_t)i * 2 + 1] = pk2(v.z, v.w);
  }
}

// ---------------- weight transpose+convert: Wt[c][k] = bf16(W[k][c]) ----------------
struct WP { const float* p[11]; };
__global__ void wtp_k(WP wp, ushort_t* __restrict__ wt) {
  int b = blockIdx.x;
  const float* W = wp.p[b];
  ushort_t* T = wt + (size_t)b * 128 * 128;
  for (int i = 0; i < 64; ++i) {
    int lin = i * 256 + threadIdx.x;
    int k = lin >> 7, c = lin & 127;
    T[c * 128 + k] = f2b(W[lin]);
  }
}

// ---------------- aggregation: one wave per node, 2 edges/step, 8B/lane ----------------
// outA[node] = dinv[node] * sum_e dinv[r_e]*ew_e*h[r_e]
// outS[node] = cinv[node] * sum_e ew_e*h[r_e]
__global__ __launch_bounds__(256) void agg_k(
    const uint_t* __restrict__ hp2, const uint2* __restrict__ sedge,
    const float* __restrict__ dinv, const float* __restrict__ cinv,
    const int* __restrict__ offs,
    uint_t* __restrict__ outA, uint_t* __restrict__ outS, int n) {
  int wid = threadIdx.x >> 6;
  int lane = threadIdx.x & 63;
  int half = lane >> 5, li = lane & 31;
  int node = blockIdx.x * 4 + wid;
  if (node >= n) return;
  int s0 = offs[node], e0 = offs[node + 1];
  float a0 = 0.f, a1 = 0.f, a2 = 0.f, a3 = 0.f;
  float m0 = 0.f, m1 = 0.f, m2 = 0.f, m3 = 0.f;
  for (int p = s0; p < e0; p += 16) {
#pragma unroll
    for (int j = 0; j < 8; ++j) {
      int k = p + j * 2 + half;
      bool ok = (k < e0);
      int kk = ok ? k : s0;
      uint2 ed = sedge[kk];
      float ew = ok ? __uint_as_float(ed.y) : 0.f;
      float dr = dinv[ed.x];
      float wA = dr * ew;
      uint2 v = *(const uint2*)&hp2[(size_t)ed.x * 64 + li * 2];
      float f0 = blo(v.x), f1 = bhi(v.x), f2 = blo(v.y), f3 = bhi(v.y);
      a0 += wA * f0; a1 += wA * f1; a2 += wA * f2; a3 += wA * f3;
      m0 += ew * f0; m1 += ew * f1; m2 += ew * f2; m3 += ew * f3;
    }
  }
  a0 += __shfl_xor(a0, 32); a1 += __shfl_xor(a1, 32);
  a2 += __shfl_xor(a2, 32); a3 += __shfl_xor(a3, 32);
  m0 += __shfl_xor(m0, 32); m1 += __shfl_xor(m1, 32);
  m2 += __shfl_xor(m2, 32); m3 += __shfl_xor(m3, 32);
  if (half == 0) {
    float dn = dinv[node];
    uint2 o;
    o.x = pk2(dn * a0, dn * a1);
    o.y = pk2(dn * a2, dn * a3);
    *(uint2*)&outA[(size_t)node * 64 + li * 2] = o;
  } else {
    float cn = cinv[node];
    uint2 o;
    o.x = pk2(cn * m0, cn * m1);
    o.y = pk2(cn * m2, cn * m3);
    *(uint2*)&outS[(size_t)node * 64 + li * 2] = o;
  }
}

// ---------------- MFMA bf16 GEMM: out = act(A1@W1 [+ A2@W2] + bias) ----------------
__device__ inline int swz(int r, int k) { return (r * 128 + k) ^ ((r & 7) << 3); }

template <int ACT, int NSRC>
__global__ __launch_bounds__(256) void mgemm_k(
    const ushort_t* __restrict__ A1, const ushort_t* __restrict__ A2,
    const ushort_t* __restrict__ Wt1, const ushort_t* __restrict__ Wt2,
    const float* __restrict__ bias, ushort_t* __restrict__ out, int nrows) {
  __shared__ ushort_t As[128 * 128];
  __shared__ ushort_t Ws[128 * 128];
  int t = threadIdx.x;
  int lane = t & 63, wid = t >> 6;
  int wr = wid >> 1, wc = wid & 1;   // 2x2 wave grid, each wave 64x64
  int rowBase = blockIdx.x * 128;
  f32x4 acc[4][4] = {};

#pragma unroll
  for (int src = 0; src < NSRC; ++src) {
    const ushort_t* A = src ? A2 : A1;
    const ushort_t* Wt = src ? Wt2 : Wt1;
    if (src) __syncthreads();
#ifdef HAS_GLL
    {
      int lr = lane >> 4;
      int lchunk = lane & 15;
#pragma unroll
      for (int i = 0; i < 8; ++i) {
        int r = wid * 32 + i * 4 + lr;
        int csrc = (lchunk ^ (r & 7)) << 4;
        const char* gA = (const char*)A + (((size_t)(rowBase + r)) << 8) + csrc;
        const char* gW = (const char*)Wt + (((size_t)r) << 8) + csrc;
        char* lA = (char*)As + ((wid * 32 + i * 4) << 8);
        char* lW = (char*)Ws + ((wid * 32 + i * 4) << 8);
        __builtin_amdgcn_global_load_lds((const __attribute__((address_space(1))) void*)gA,
                                         (__attribute__((address_space(3))) void*)lA, 16, 0, 0);
        __builtin_amdgcn_global_load_lds((const __attribute__((address_space(1))) void*)gW,
                                         (__attribute__((address_space(3))) void*)lW, 16, 0, 0);
      }
      asm volatile("s_waitcnt vmcnt(0)" ::: "memory");
    }
#else
    {
#pragma unroll
      for (int i = 0; i < 8; ++i) {
        int f = t + i * 256;
        int r = f >> 4;
        int kq = (f & 15) * 8;
        *(uint4*)&As[swz(r, kq)] = *(const uint4*)&A[(size_t)(rowBase + r) * 128 + kq];
        *(uint4*)&Ws[swz(r, kq)] = *(const uint4*)&Wt[(size_t)r * 128 + kq];
      }
    }
#endif
    __syncthreads();
#pragma unroll
    for (int k = 0; k < 4; ++k) {
      bf16x8 af[4], bfr[4];
#pragma unroll
      for (int m = 0; m < 4; ++m)
        af[m] = *(const bf16x8*)&As[swz(wr * 64 + m * 16 + (lane & 15), k * 32 + (lane >> 4) * 8)];
#pragma unroll
      for (int nn = 0; nn < 4; ++nn)
        bfr[nn] = *(const bf16x8*)&Ws[swz(wc * 64 + nn * 16 + (lane & 15), k * 32 + (lane >> 4) * 8)];
#pragma unroll
      for (int m = 0; m < 4; ++m)
#pragma unroll
        for (int nn = 0; nn < 4; ++nn)
          acc[m][nn] = __builtin_amdgcn_mfma_f32_16x16x32_bf16(af[m], bfr[nn], acc[m][nn], 0, 0, 0);
    }
  }
#pragma unroll
  for (int m = 0; m < 4; ++m) {
    int gr0 = rowBase + wr * 64 + m * 16 + (lane >> 4) * 4;
#pragma unroll
    for (int nn = 0; nn < 4; ++nn) {
      int gc = wc * 64 + nn * 16 + (lane & 15);
      float bv = bias[gc];
#pragma unroll
      for (int j = 0; j < 4; ++j) {
        int gr = gr0 + j;
        if (gr < nrows) {
          float v = acc[m][nn][j] + bv;
          if (ACT == 1) v = fmaxf(v, 0.f);
          if (ACT == 2) v = v > 0.f ? v : (__expf(0.01f * v) - 1.f);
          out[(size_t)gr * 128 + gc] = f2b(v);
        }
      }
    }
  }
}

// ---------------- classifier ----------------
__global__ __launch_bounds__(256) void cls_k(
    const ushort_t* __restrict__ h1, const ushort_t* __restrict__ h2,
    const float* __restrict__ W, const float* __restrict__ b,
    float* __restrict__ out, int n) {
  __shared__ float hs[16][260];
  __shared__ float Wl[4096];
  int t = threadIdx.x;
  int c = t & 15, nl = t >> 4;
  int n0 = blockIdx.x * 16;
#pragma unroll
  for (int i = 0; i < 4; ++i) {
    int idx = t + i * 256;
    *(float4*)&Wl[idx * 4] = *(const float4*)&W[idx * 4];
  }
#pragma unroll
  for (int i = 0; i < 2; ++i) {
    int f = t + i * 256;
    int node = f >> 5;
    int q = f & 31;
    int gn = n0 + node;
    uint4 v = make_uint4(0, 0, 0, 0);
    if (gn < n)
      v = (q < 16) ? *(const uint4*)&h1[(size_t)gn * 128 + q * 8]
                   : *(const uint4*)&h2[(size_t)gn * 128 + (q - 16) * 8];
    int base = q * 8;
    uint_t u[4] = {v.x, v.y, v.z, v.w};
#pragma unroll
    for (int j = 0; j < 4; ++j) {
      hs[node][base + 2 * j]     = blo(u[j]);
      hs[node][base + 2 * j + 1] = bhi(u[j]);
    }
  }
  __syncthreads();
  float acc = b[c];
#pragma unroll 8
  for (int k = 0; k < 256; ++k) acc += hs[nl][k] * Wl[k * 16 + c];
  float mx = acc;
  for (int d = 1; d < 16; d <<= 1) mx = fmaxf(mx, __shfl_xor(mx, d));
  float ex = __expf(acc - mx);
  float sum = ex;
  for (int d = 1; d < 16; d <<= 1) sum += __shfl_xor(sum, d);
  float r = (acc - mx) - logf(sum);
  int gn = n0 + nl;
  if (gn < n) out[gn * 16 + c] = r;
}

// ---------------- launch ----------------

extern "C" void kernel_launch(void* const* d_in, const int* in_sizes, int n_in,
                              void* d_out, int out_size, void* d_ws, size_t ws_size,
                              hipStream_t stream) {
  const float* x        = (const float*)d_in[0];
  const int*   eidx     = (const int*)d_in[1];
  const float* ew       = (const float*)d_in[2];
  const float* pre_w0   = (const float*)d_in[3];
  const float* pre_b0   = (const float*)d_in[4];
  const float* arma_w0  = (const float*)d_in[5];
  const float* arma_v0  = (const float*)d_in[6];
  const float* arma_b0  = (const float*)d_in[7];
  const float* sage_wl0 = (const float*)d_in[8];
  const float* sage_bl0 = (const float*)d_in[9];
  const float* sage_wr0 = (const float*)d_in[10];
  const float* pre_w1   = (const float*)d_in[11];
  const float* pre_b1   = (const float*)d_in[12];
  const float* arma_w1  = (const float*)d_in[13];
  const float* arma_v1  = (const float*)d_in[14];
  const float* arma_b1  = (const float*)d_in[15];
  const float* sage_wl1 = (const float*)d_in[16];
  const float* sage_bl1 = (const float*)d_in[17];
  const float* sage_wr1 = (const float*)d_in[18];
  const float* cls_w    = (const float*)d_in[19];
  const float* cls_b    = (const float*)d_in[20];

  const int N = in_sizes[0] / 128;
  const int E = in_sizes[2];
  const int N_pad = ((N + 127) / 128) * 128;
  const int NB = (N + 511) >> 9;  // 512 nodes per bucket, NB <= 256 for N <= 131072
  const int* row = eidx;
  const int* col = eidx + E;

  char* p = (char*)d_ws;
  auto carve = [&](size_t bytes) { char* q = p; p += (bytes + 255) & ~(size_t)255; return q; };
  ushort_t* hp    = (ushort_t*)carve((size_t)N_pad * 128 * 2);
  ushort_t* bufA  = (ushort_t*)carve((size_t)N_pad * 128 * 2);
  ushort_t* bufS  = (ushort_t*)carve((size_t)N_pad * 128 * 2);
  ushort_t* xb    = (ushort_t*)carve((size_t)N_pad * 128 * 2);
  ushort_t* wt    = (ushort_t*)carve((size_t)11 * 128 * 128 * 2);
  uint2*  sedge  = (uint2*)carve((size_t)E * 8);
  uint2*  sedgeT = (uint2*)carve((size_t)E * 8);
  float*  dinv  = (float*)carve((size_t)N * 4);
  float*  cinv  = (float*)carve((size_t)N * 4);
  int*    offs  = (int*)carve((size_t)(N + 1) * 4);
  int*    bcnt  = (int*)carve((size_t)256 * 4);
  int*    bbase = (int*)carve((size_t)257 * 4);
  int*    cursor= (int*)carve((size_t)256 * 4);

  hipMemsetAsync(bcnt, 0, (size_t)256 * 4, stream);

  const int gE = (E + 8191) / 8192;
  bcount_k<<<gE, 256, 0, stream>>>(col, bcnt, E, NB);
  bscan_k<<<1, 256, 0, stream>>>(bcnt, bbase, cursor, offs, NB, N, E);
  bscatter_k<<<gE, 256, 0, stream>>>(row, col, ew, cursor, sedgeT, E, NB);
  bsort_k<<<NB, 256, 0, stream>>>(sedgeT, bbase, offs, dinv, cinv, sedge, N);

  cvt_k<<<(N * 128 / 4 + 255) / 256, 256, 0, stream>>>(x, (uint_t*)xb, N * 128 / 4);
  WP wp;
  wp.p[0] = pre_w0;  wp.p[1] = arma_w0; wp.p[2] = arma_v0;
  wp.p[3] = sage_wl0; wp.p[4] = sage_wr0;
  wp.p[5] = pre_w1;  wp.p[6] = pre_w1 + 128 * 128;
  wp.p[7] = arma_w1; wp.p[8] = arma_v1;
  wp.p[9] = sage_wl1; wp.p[10] = sage_wr1;
  wtp_k<<<11, 256, 0, stream>>>(wp, wt);

  const int gB = (N + 127) / 128;
  const int gA = (N + 3) / 4;
  auto WT = [&](int i) { return wt + (size_t)i * 128 * 128; };

  // ---- cell 0 ----
  mgemm_k<0, 1><<<gB, 256, 0, stream>>>(xb, nullptr, WT(0), nullptr, pre_b0, hp, N);
  agg_k<<<gA, 256, 0, stream>>>((const uint_t*)hp, sedge, dinv, cinv, offs, (uint_t*)bufA, (uint_t*)bufS, N);
  mgemm_k<1, 2><<<gB, 256, 0, stream>>>(bufA, hp, WT(1), WT(2), arma_b0, bufA, N);
  mgemm_k<2, 2><<<gB, 256, 0, stream>>>(bufS, hp, WT(3), WT(4), sage_bl0, bufS, N);
  // ---- cell 1 ----
  mgemm_k<0, 2><<<gB, 256, 0, stream>>>(bufA, bufS, WT(5), WT(6), pre_b1, hp, N);
  agg_k<<<gA, 256, 0, stream>>>((const uint_t*)hp, sedge, dinv, cinv, offs, (uint_t*)bufA, (uint_t*)bufS, N);
  mgemm_k<1, 2><<<gB, 256, 0, stream>>>(bufA, hp, WT(7), WT(8), arma_b1, bufA, N);
  mgemm_k<2, 2><<<gB, 256, 0, stream>>>(bufS, hp, WT(9), WT(10), sage_bl1, bufS, N);
  // ---- classifier ----
  cls_k<<<(N + 15) / 16, 256, 0, stream>>>(bufA, bufS, cls_w, cls_b, (float*)d_out, N);
}

// Round 6
// 475.616 us; speedup vs baseline: 2.4695x; 1.0179x over previous
//
#include <hip/hip_runtime.h>
#include <hip/hip_bf16.h>
#include <hip/hip_fp16.h>

typedef __bf16 bf16x8 __attribute__((ext_vector_type(8)));
typedef float f32x4 __attribute__((ext_vector_type(4)));
typedef unsigned short ushort_t;
typedef unsigned int uint_t;

#if defined(__has_builtin)
#if __has_builtin(__builtin_amdgcn_global_load_lds)
#define HAS_GLL 1
#endif
#endif

// ---- bf16 helpers (storage = ushort) ----
__device__ inline float blo(uint_t v) { return __uint_as_float(v << 16); }
__device__ inline float bhi(uint_t v) { return __uint_as_float(v & 0xffff0000u); }
__device__ inline ushort_t f2b(float f) {  // RTNE
  uint_t u = __float_as_uint(f);
  uint_t r = (u + 0x7fffu + ((u >> 16) & 1u)) >> 16;
  return (ushort_t)r;
}
__device__ inline uint_t pk2(float a, float b) {
  return (uint_t)f2b(a) | ((uint_t)f2b(b) << 16);
}

// ================= CSR build via 2-pass bucket sort =================
// bucket = col >> 9 (512 nodes per bucket). NB <= 256 (N <= 131072).

__global__ __launch_bounds__(256) void bcount_k(const int* __restrict__ col,
                                                int* __restrict__ bcnt, int E, int NB) {
  __shared__ int h[256];
  int t = threadIdx.x;
  h[t] = 0;
  __syncthreads();
  int e0 = blockIdx.x * 8192;
#pragma unroll
  for (int j = 0; j < 32; ++j) {
    int e = e0 + j * 256 + t;
    if (e < E) atomicAdd(&h[col[e] >> 9], 1);
  }
  __syncthreads();
  if (t < NB && h[t] > 0) atomicAdd(&bcnt[t], h[t]);
}

__global__ __launch_bounds__(256) void bscan_k(const int* __restrict__ bcnt,
                                               int* __restrict__ bbase, int* __restrict__ cursor,
                                               int* __restrict__ offs, int NB, int N, int E) {
  __shared__ int sd[256];
  int t = threadIdx.x;
  int v = (t < NB) ? bcnt[t] : 0;
  int acc = v;
  sd[t] = v; __syncthreads();
  for (int off = 1; off < 256; off <<= 1) {
    int x = (t >= off) ? sd[t - off] : 0;
    __syncthreads();
    acc += x; sd[t] = acc;
    __syncthreads();
  }
  if (t < NB) { bbase[t] = acc - v; cursor[t] = acc - v; }
  if (t == 0) { bbase[NB] = E; offs[N] = E; }
}

__global__ __launch_bounds__(256) void bscatter_k(
    const int* __restrict__ row, const int* __restrict__ col, const float* __restrict__ ew,
    int* __restrict__ cursor, uint2* __restrict__ eout, int E, int NB) {
  __shared__ int h[256];
  __shared__ int lofs[256];
  __shared__ int lcur[256];
  __shared__ int gbase[256];
  __shared__ uint2 stage[8192];
  __shared__ int addr[8192];
  int t = threadIdx.x;
  int e0 = blockIdx.x * 8192;
  int cnt = min(8192, E - e0);
  h[t] = 0;
  __syncthreads();
#pragma unroll
  for (int j = 0; j < 32; ++j) {
    int e = e0 + j * 256 + t;
    if (e < E) atomicAdd(&h[col[e] >> 9], 1);
  }
  __syncthreads();
  int s = h[t];
  int acc = s;
  lofs[t] = s; __syncthreads();
  for (int off = 1; off < 256; off <<= 1) {
    int x = (t >= off) ? lofs[t - off] : 0;
    __syncthreads();
    acc += x; lofs[t] = acc;
    __syncthreads();
  }
  int excl = acc - s;
  if (t < NB && s > 0) gbase[t] = atomicAdd(&cursor[t], s);
  __syncthreads();
  lofs[t] = excl;
  lcur[t] = excl;
  __syncthreads();
#pragma unroll
  for (int j = 0; j < 32; ++j) {
    int e = e0 + j * 256 + t;
    if (e < E) {
      int c = col[e];
      int bk = c >> 9;
      int p = atomicAdd(&lcur[bk], 1);
      uint2 v;
      v.x = ((uint_t)(c & 511) << 17) | (uint_t)row[e];
      v.y = __float_as_uint(ew[e]);
      stage[p] = v;
      addr[p] = gbase[bk] + (p - lofs[bk]);
    }
  }
  __syncthreads();
  for (int i = t; i < cnt; i += 256) eout[addr[i]] = stage[i];
}

__global__ __launch_bounds__(256) void bsort_k(
    const uint2* __restrict__ ein, const int* __restrict__ bbase,
    int* __restrict__ offs, float* __restrict__ dinv, float* __restrict__ cinv,
    uint2* __restrict__ eout, int N) {
  __shared__ int h[512];
  __shared__ int lofs[512];
  __shared__ int lcur[512];
  __shared__ float degs[512];
  __shared__ int sd[256];
  __shared__ uint2 stage[14336];
  int t = threadIdx.x, b = blockIdx.x;
  int base = bbase[b], end = bbase[b + 1];
  int cnt = end - base;
  int node0 = b << 9;
  h[t] = 0; h[t + 256] = 0;
  degs[t] = 0.f; degs[t + 256] = 0.f;
  __syncthreads();
  for (int i = t; i < cnt; i += 256) {
    uint2 v = ein[base + i];
    int lc = v.x >> 17;
    atomicAdd(&h[lc], 1);
    atomicAdd(&degs[lc], __uint_as_float(v.y));
  }
  __syncthreads();
  int s = h[2 * t] + h[2 * t + 1];
  int acc = s;
  sd[t] = s; __syncthreads();
  for (int off = 1; off < 256; off <<= 1) {
    int x = (t >= off) ? sd[t - off] : 0;
    __syncthreads();
    acc += x; sd[t] = acc;
    __syncthreads();
  }
  int excl = acc - s;
  lofs[2 * t] = excl;
  lofs[2 * t + 1] = excl + h[2 * t];
  lcur[2 * t] = excl;
  lcur[2 * t + 1] = excl + h[2 * t];
  __syncthreads();
  for (int j = t; j < 512; j += 256) {
    int node = node0 + j;
    if (node < N) {
      offs[node] = base + lofs[j];
      float d = degs[j];
      dinv[node] = d > 0.f ? rsqrtf(d) : 0.f;
      cinv[node] = 1.0f / fmaxf((float)h[j], 1.f);
    }
  }
  for (int i = t; i < cnt; i += 256) {
    uint2 v = ein[base + i];
    int lc = v.x >> 17;
    int p = atomicAdd(&lcur[lc], 1);
    uint2 o;
    o.x = v.x & 0x1FFFF;
    o.y = v.y;
    stage[p] = o;
  }
  __syncthreads();
  for (int i = t; i < cnt; i += 256) eout[base + i] = stage[i];
}

// pack per-edge weights: {f16(dinv[row]*ew) | f16(ew)<<16}
__global__ void edgew_k(uint2* __restrict__ sedge, const float* __restrict__ dinv, int E) {
  int e = blockIdx.x * blockDim.x + threadIdx.x;
  if (e < E) {
    uint2 v = sedge[e];
    float ew = __uint_as_float(v.y);
    float wA = dinv[v.x] * ew;
    uint_t lo = (uint_t)__half_as_ushort(__float2half_rn(wA));
    uint_t hi = (uint_t)__half_as_ushort(__float2half_rn(ew));
    sedge[e].y = lo | (hi << 16);
  }
}

// ---------------- weight transpose+convert: Wt[c][k] = bf16(W[k][c]) ----------------
struct WP { const float* p[11]; };
__global__ void wtp_k(WP wp, ushort_t* __restrict__ wt) {
  int b = blockIdx.x;
  const float* W = wp.p[b];
  ushort_t* T = wt + (size_t)b * 128 * 128;
  for (int i = 0; i < 64; ++i) {
    int lin = i * 256 + threadIdx.x;
    int k = lin >> 7, c = lin & 127;
    T[c * 128 + k] = f2b(W[lin]);
  }
}

// ---------------- aggregation: half-wave per node, 8 edges/iter ----------------
__global__ __launch_bounds__(256) void agg_k(
    const uint_t* __restrict__ hp2, const uint2* __restrict__ sedge,
    const float* __restrict__ dinv, const float* __restrict__ cinv,
    const int* __restrict__ offs,
    uint_t* __restrict__ outA, uint_t* __restrict__ outS, int n) {
  int wid = threadIdx.x >> 6;
  int lane = threadIdx.x & 63;
  int half = lane >> 5, li = lane & 31;
  int node = blockIdx.x * 8 + wid * 2 + half;
  if (node >= n) return;
  int s0 = offs[node], e0 = offs[node + 1];
  float a0 = 0.f, a1 = 0.f, a2 = 0.f, a3 = 0.f;
  float m0 = 0.f, m1 = 0.f, m2 = 0.f, m3 = 0.f;
  for (int p = s0; p < e0; p += 8) {
    uint2 ed[8];
#pragma unroll
    for (int j = 0; j < 8; ++j) {
      int k = p + j;
      ed[j] = sedge[k < e0 ? k : s0];
    }
#pragma unroll
    for (int j = 0; j < 8; ++j) {
      bool ok = (p + j < e0);
      uint_t w = ok ? ed[j].y : 0u;
      uint2 v = *(const uint2*)&hp2[(size_t)ed[j].x * 64 + li * 2];
      float wA = __half2float(__ushort_as_half((ushort_t)(w & 0xffff)));
      float wS = __half2float(__ushort_as_half((ushort_t)(w >> 16)));
      float f0 = blo(v.x), f1 = bhi(v.x), f2 = blo(v.y), f3 = bhi(v.y);
      a0 += wA * f0; a1 += wA * f1; a2 += wA * f2; a3 += wA * f3;
      m0 += wS * f0; m1 += wS * f1; m2 += wS * f2; m3 += wS * f3;
    }
  }
  float dn = dinv[node], cn = cinv[node];
  uint2 oA, oS;
  oA.x = pk2(dn * a0, dn * a1); oA.y = pk2(dn * a2, dn * a3);
  oS.x = pk2(cn * m0, cn * m1); oS.y = pk2(cn * m2, cn * m3);
  *(uint2*)&outA[(size_t)node * 64 + li * 2] = oA;
  *(uint2*)&outS[(size_t)node * 64 + li * 2] = oS;
}

// ---------------- GEMM building blocks ----------------
__device__ inline int swz(int r, int k) { return (r * 128 + k) ^ ((r & 7) << 3); }

// stage one 128x128 bf16 tile into LDS (swizzled), rows rowBase..rowBase+127
__device__ inline void stage_tile(const ushort_t* __restrict__ A, ushort_t* lds,
                                  int rowBase, int wid, int lane) {
  int lr = lane >> 4, lchunk = lane & 15;
#ifdef HAS_GLL
#pragma unroll
  for (int i = 0; i < 8; ++i) {
    int r = wid * 32 + i * 4 + lr;
    int csrc = (lchunk ^ (r & 7)) << 4;
    const char* g = (const char*)A + (((size_t)(rowBase + r)) << 8) + csrc;
    char* l = (char*)lds + ((wid * 32 + i * 4) << 8);
    __builtin_amdgcn_global_load_lds((const __attribute__((address_space(1))) void*)g,
                                     (__attribute__((address_space(3))) void*)l, 16, 0, 0);
  }
#else
#pragma unroll
  for (int i = 0; i < 8; ++i) {
    int r = wid * 32 + i * 4 + lr;
    uint4 v = *(const uint4*)&A[((size_t)(rowBase + r)) * 128 + lchunk * 8];
    *(uint4*)&lds[swz(r, lchunk * 8)] = v;
  }
#endif
}

__device__ inline void stage_wait() {
#ifdef HAS_GLL
  asm volatile("s_waitcnt vmcnt(0)" ::: "memory");
#endif
}

// W fragment from global (Wt row-major [128 c][128 k] bf16)
__device__ inline bf16x8 ldw(const ushort_t* __restrict__ Wt, int wc, int nn, int k, int lane) {
  int c = wc * 64 + nn * 16 + (lane & 15);
  return *(const bf16x8*)&Wt[c * 128 + k * 32 + (lane >> 4) * 8];
}

__device__ inline bf16x8 lda(const ushort_t* lds, int wr, int m, int k, int lane) {
  return *(const bf16x8*)&lds[swz(wr * 64 + m * 16 + (lane & 15), k * 32 + (lane >> 4) * 8)];
}

template <int ACT>
__device__ inline void epilogue(f32x4 (&acc)[4][4], const float* __restrict__ bias,
                                ushort_t* __restrict__ out, int rowBase, int wr, int wc,
                                int lane, int nrows) {
#pragma unroll
  for (int m = 0; m < 4; ++m) {
    int gr0 = rowBase + wr * 64 + m * 16 + (lane >> 4) * 4;
#pragma unroll
    for (int nn = 0; nn < 4; ++nn) {
      int gc = wc * 64 + nn * 16 + (lane & 15);
      float bv = bias[gc];
#pragma unroll
      for (int j = 0; j < 4; ++j) {
        int gr = gr0 + j;
        if (gr < nrows) {
          float v = acc[m][nn][j] + bv;
          if (ACT == 1) v = fmaxf(v, 0.f);
          if (ACT == 2) v = v > 0.f ? v : (__expf(0.01f * v) - 1.f);
          out[(size_t)gr * 128 + gc] = f2b(v);
        }
      }
    }
  }
}

// ---------------- pre0: f32 input, single source ----------------
__global__ __launch_bounds__(256, 2) void pre0_k(
    const float* __restrict__ Xf, const ushort_t* __restrict__ Wt,
    const float* __restrict__ bias, ushort_t* __restrict__ out, int nrows) {
  __shared__ ushort_t As[128 * 128];
  int t = threadIdx.x, lane = t & 63, wid = t >> 6;
  int wr = wid >> 1, wc = wid & 1;
  int rowBase = blockIdx.x * 128;
#pragma unroll
  for (int i = 0; i < 16; ++i) {
    int f = t + i * 256;
    int r = f >> 5, q = f & 31;
    int gr = rowBase + r;
    float4 v = make_float4(0.f, 0.f, 0.f, 0.f);
    if (gr < nrows) v = *(const float4*)&Xf[(size_t)gr * 128 + q * 4];
    uint2 o;
    o.x = pk2(v.x, v.y);
    o.y = pk2(v.z, v.w);
    *(uint2*)&As[swz(r, q * 4)] = o;
  }
  __syncthreads();
  f32x4 acc[4][4] = {};
#pragma unroll
  for (int k = 0; k < 4; ++k) {
    bf16x8 af[4], wf[4];
#pragma unroll
    for (int m = 0; m < 4; ++m) af[m] = lda(As, wr, m, k, lane);
#pragma unroll
    for (int nn = 0; nn < 4; ++nn) wf[nn] = ldw(Wt, wc, nn, k, lane);
#pragma unroll
    for (int m = 0; m < 4; ++m)
#pragma unroll
      for (int nn = 0; nn < 4; ++nn)
        acc[m][nn] = __builtin_amdgcn_mfma_f32_16x16x32_bf16(af[m], wf[nn], acc[m][nn], 0, 0, 0);
  }
  epilogue<0>(acc, bias, out, rowBase, wr, wc, lane, nrows);
}

// ---------------- gemm1: bf16 sources (1 or 2), W from global ----------------
template <int ACT, int NSRC>
__global__ __launch_bounds__(256, 2) void gemm1_k(
    const ushort_t* __restrict__ A1, const ushort_t* __restrict__ A2,
    const ushort_t* __restrict__ Wt1, const ushort_t* __restrict__ Wt2,
    const float* __restrict__ bias, ushort_t* __restrict__ out, int nrows) {
  __shared__ ushort_t As[128 * 128];
  int t = threadIdx.x, lane = t & 63, wid = t >> 6;
  int wr = wid >> 1, wc = wid & 1;
  int rowBase = blockIdx.x * 128;
  f32x4 acc[4][4] = {};
#pragma unroll
  for (int src = 0; src < NSRC; ++src) {
    const ushort_t* A = src ? A2 : A1;
    const ushort_t* Wt = src ? Wt2 : Wt1;
    if (src) __syncthreads();
    stage_tile(A, As, rowBase, wid, lane);
    stage_wait();
    __syncthreads();
#pragma unroll
    for (int k = 0; k < 4; ++k) {
      bf16x8 af[4], wf[4];
#pragma unroll
      for (int m = 0; m < 4; ++m) af[m] = lda(As, wr, m, k, lane);
#pragma unroll
      for (int nn = 0; nn < 4; ++nn) wf[nn] = ldw(Wt, wc, nn, k, lane);
#pragma unroll
      for (int m = 0; m < 4; ++m)
#pragma unroll
        for (int nn = 0; nn < 4; ++nn)
          acc[m][nn] = __builtin_amdgcn_mfma_f32_16x16x32_bf16(af[m], wf[nn], acc[m][nn], 0, 0, 0);
    }
  }
  epilogue<ACT>(acc, bias, out, rowBase, wr, wc, lane, nrows);
}

// ---------------- fused ARMA+SAGE: h1 = relu(X@WX + H@WXH + bX), h2 = elu(lrelu(Y@WY + H@WYH + bY))
__global__ __launch_bounds__(256, 2) void dualgemm_k(
    const ushort_t* __restrict__ X, const ushort_t* __restrict__ Y,
    const ushort_t* __restrict__ H,
    const ushort_t* __restrict__ WX, const ushort_t* __restrict__ WXH,
    const ushort_t* __restrict__ WY, const ushort_t* __restrict__ WYH,
    const float* __restrict__ bX, const float* __restrict__ bY,
    ushort_t* __restrict__ outX, ushort_t* __restrict__ outY, int nrows) {
  __shared__ ushort_t Xs[128 * 128];
  __shared__ ushort_t Hs[128 * 128];
  int t = threadIdx.x, lane = t & 63, wid = t >> 6;
  int wr = wid >> 1, wc = wid & 1;
  int rowBase = blockIdx.x * 128;

  stage_tile(X, Xs, rowBase, wid, lane);
  stage_tile(H, Hs, rowBase, wid, lane);
  stage_wait();
  __syncthreads();

  {
    f32x4 acc[4][4] = {};
#pragma unroll
    for (int k = 0; k < 4; ++k) {
      bf16x8 af[4], hf[4], wx[4], wh[4];
#pragma unroll
      for (int m = 0; m < 4; ++m) { af[m] = lda(Xs, wr, m, k, lane); hf[m] = lda(Hs, wr, m, k, lane); }
#pragma unroll
      for (int nn = 0; nn < 4; ++nn) { wx[nn] = ldw(WX, wc, nn, k, lane); wh[nn] = ldw(WXH, wc, nn, k, lane); }
#pragma unroll
      for (int m = 0; m < 4; ++m)
#pragma unroll
        for (int nn = 0; nn < 4; ++nn) {
          acc[m][nn] = __builtin_amdgcn_mfma_f32_16x16x32_bf16(af[m], wx[nn], acc[m][nn], 0, 0, 0);
          acc[m][nn] = __builtin_amdgcn_mfma_f32_16x16x32_bf16(hf[m], wh[nn], acc[m][nn], 0, 0, 0);
        }
    }
    epilogue<1>(acc, bX, outX, rowBase, wr, wc, lane, nrows);
  }

  __syncthreads();               // all reads of Xs finished
  stage_tile(Y, Xs, rowBase, wid, lane);
  stage_wait();
  __syncthreads();

  {
    f32x4 acc[4][4] = {};
#pragma unroll
    for (int k = 0; k < 4; ++k) {
      bf16x8 af[4], hf[4], wy[4], wh[4];
#pragma unroll
      for (int m = 0; m < 4; ++m) { af[m] = lda(Xs, wr, m, k, lane); hf[m] = lda(Hs, wr, m, k, lane); }
#pragma unroll
      for (int nn = 0; nn < 4; ++nn) { wy[nn] = ldw(WY, wc, nn, k, lane); wh[nn] = ldw(WYH, wc, nn, k, lane); }
#pragma unroll
      for (int m = 0; m < 4; ++m)
#pragma unroll
        for (int nn = 0; nn < 4; ++nn) {
          acc[m][nn] = __builtin_amdgcn_mfma_f32_16x16x32_bf16(af[m], wy[nn], acc[m][nn], 0, 0, 0);
          acc[m][nn] = __builtin_amdgcn_mfma_f32_16x16x32_bf16(hf[m], wh[nn], acc[m][nn], 0, 0, 0);
        }
    }
    epilogue<2>(acc, bY, outY, rowBase, wr, wc, lane, nrows);
  }
}

// ---------------- classifier ----------------
__global__ __launch_bounds__(256) void cls_k(
    const ushort_t* __restrict__ h1, const ushort_t* __restrict__ h2,
    const float* __restrict__ W, const float* __restrict__ b,
    float* __restrict__ out, int n) {
  __shared__ float hs[16][260];
  __shared__ float Wl[4096];
  int t = threadIdx.x;
  int c = t & 15, nl = t >> 4;
  int n0 = blockIdx.x * 16;
#pragma unroll
  for (int i = 0; i < 4; ++i) {
    int idx = t + i * 256;
    *(float4*)&Wl[idx * 4] = *(const float4*)&W[idx * 4];
  }
#pragma unroll
  for (int i = 0; i < 2; ++i) {
    int f = t + i * 256;
    int node = f >> 5;
    int q = f & 31;
    int gn = n0 + node;
    uint4 v = make_uint4(0, 0, 0, 0);
    if (gn < n)
      v = (q < 16) ? *(const uint4*)&h1[(size_t)gn * 128 + q * 8]
                   : *(const uint4*)&h2[(size_t)gn * 128 + (q - 16) * 8];
    int base = q * 8;
    uint_t u[4] = {v.x, v.y, v.z, v.w};
#pragma unroll
    for (int j = 0; j < 4; ++j) {
      hs[node][base + 2 * j]     = blo(u[j]);
      hs[node][base + 2 * j + 1] = bhi(u[j]);
    }
  }
  __syncthreads();
  float acc = b[c];
#pragma unroll 8
  for (int k = 0; k < 256; ++k) acc += hs[nl][k] * Wl[k * 16 + c];
  float mx = acc;
  for (int d = 1; d < 16; d <<= 1) mx = fmaxf(mx, __shfl_xor(mx, d));
  float ex = __expf(acc - mx);
  float sum = ex;
  for (int d = 1; d < 16; d <<= 1) sum += __shfl_xor(sum, d);
  float r = (acc - mx) - logf(sum);
  int gn = n0 + nl;
  if (gn < n) out[gn * 16 + c] = r;
}

// ---------------- launch ----------------

extern "C" void kernel_launch(void* const* d_in, const int* in_sizes, int n_in,
                              void* d_out, int out_size, void* d_ws, size_t ws_size,
                              hipStream_t stream) {
  const float* x        = (const float*)d_in[0];
  const int*   eidx     = (const int*)d_in[1];
  const float* ew       = (const float*)d_in[2];
  const float* pre_w0   = (const float*)d_in[3];
  const float* pre_b0   = (const float*)d_in[4];
  const float* arma_w0  = (const float*)d_in[5];
  const float* arma_v0  = (const float*)d_in[6];
  const float* arma_b0  = (const float*)d_in[7];
  const float* sage_wl0 = (const float*)d_in[8];
  const float* sage_bl0 = (const float*)d_in[9];
  const float* sage_wr0 = (const float*)d_in[10];
  const float* pre_w1   = (const float*)d_in[11];
  const float* pre_b1   = (const float*)d_in[12];
  const float* arma_w1  = (const float*)d_in[13];
  const float* arma_v1  = (const float*)d_in[14];
  const float* arma_b1  = (const float*)d_in[15];
  const float* sage_wl1 = (const float*)d_in[16];
  const float* sage_bl1 = (const float*)d_in[17];
  const float* sage_wr1 = (const float*)d_in[18];
  const float* cls_w    = (const float*)d_in[19];
  const float* cls_b    = (const float*)d_in[20];

  const int N = in_sizes[0] / 128;
  const int E = in_sizes[2];
  const int N_pad = ((N + 127) / 128) * 128;
  const int NB = (N + 511) >> 9;
  const int* row = eidx;
  const int* col = eidx + E;

  char* p = (char*)d_ws;
  auto carve = [&](size_t bytes) { char* q = p; p += (bytes + 255) & ~(size_t)255; return q; };
  ushort_t* hp    = (ushort_t*)carve((size_t)N_pad * 128 * 2);
  ushort_t* bufA  = (ushort_t*)carve((size_t)N_pad * 128 * 2);
  ushort_t* bufS  = (ushort_t*)carve((size_t)N_pad * 128 * 2);
  ushort_t* wt    = (ushort_t*)carve((size_t)11 * 128 * 128 * 2);
  uint2*  sedge  = (uint2*)carve((size_t)E * 8);
  uint2*  sedgeT = (uint2*)carve((size_t)E * 8);
  float*  dinv  = (float*)carve((size_t)N * 4);
  float*  cinv  = (float*)carve((size_t)N * 4);
  int*    offs  = (int*)carve((size_t)(N + 1) * 4);
  int*    bcnt  = (int*)carve((size_t)256 * 4);
  int*    bbase = (int*)carve((size_t)257 * 4);
  int*    cursor= (int*)carve((size_t)256 * 4);

  hipMemsetAsync(bcnt, 0, (size_t)256 * 4, stream);

  const int gE = (E + 8191) / 8192;
  bcount_k<<<gE, 256, 0, stream>>>(col, bcnt, E, NB);
  bscan_k<<<1, 256, 0, stream>>>(bcnt, bbase, cursor, offs, NB, N, E);
  bscatter_k<<<gE, 256, 0, stream>>>(row, col, ew, cursor, sedgeT, E, NB);
  bsort_k<<<NB, 256, 0, stream>>>(sedgeT, bbase, offs, dinv, cinv, sedge, N);
  edgew_k<<<(E + 255) / 256, 256, 0, stream>>>(sedge, dinv, E);

  WP wp;
  wp.p[0] = pre_w0;  wp.p[1] = arma_w0; wp.p[2] = arma_v0;
  wp.p[3] = sage_wl0; wp.p[4] = sage_wr0;
  wp.p[5] = pre_w1;  wp.p[6] = pre_w1 + 128 * 128;
  wp.p[7] = arma_w1; wp.p[8] = arma_v1;
  wp.p[9] = sage_wl1; wp.p[10] = sage_wr1;
  wtp_k<<<11, 256, 0, stream>>>(wp, wt);

  const int gB = (N + 127) / 128;
  const int gA = (N + 7) / 8;
  auto WT = [&](int i) { return wt + (size_t)i * 128 * 128; };

  // ---- cell 0 ----
  pre0_k<<<gB, 256, 0, stream>>>(x, WT(0), pre_b0, hp, N);
  agg_k<<<gA, 256, 0, stream>>>((const uint_t*)hp, sedge, dinv, cinv, offs, (uint_t*)bufA, (uint_t*)bufS, N);
  dualgemm_k<<<gB, 256, 0, stream>>>(bufA, bufS, hp, WT(1), WT(2), WT(3), WT(4),
                                     arma_b0, sage_bl0, bufA, bufS, N);
  // ---- cell 1 ----
  gemm1_k<0, 2><<<gB, 256, 0, stream>>>(bufA, bufS, WT(5), WT(6), pre_b1, hp, N);
  agg_k<<<gA, 256, 0, stream>>>((const uint_t*)hp, sedge, dinv, cinv, offs, (uint_t*)bufA, (uint_t*)bufS, N);
  dualgemm_k<<<gB, 256, 0, stream>>>(bufA, bufS, hp, WT(7), WT(8), WT(9), WT(10),
                                     arma_b1, sage_bl1, bufA, bufS, N);
  // ---- classifier ----
  cls_k<<<(N + 15) / 16, 256, 0, stream>>>(bufA, bufS, cls_w, cls_b, (float*)d_out, N);
}

// Round 7
// 377.834 us; speedup vs baseline: 3.1086x; 1.2588x over previous
//
#include <hip/hip_runtime.h>
#include <hip/hip_bf16.h>
#include <hip/hip_fp16.h>

typedef __bf16 bf16x8 __attribute__((ext_vector_type(8)));
typedef float f32x4 __attribute__((ext_vector_type(4)));
typedef unsigned short ushort_t;
typedef unsigned int uint_t;

#if defined(__has_builtin)
#if __has_builtin(__builtin_amdgcn_global_load_lds)
#define HAS_GLL 1
#endif
#endif

// ---- bf16 helpers (storage = ushort) ----
__device__ inline float blo(uint_t v) { return __uint_as_float(v << 16); }
__device__ inline float bhi(uint_t v) { return __uint_as_float(v & 0xffff0000u); }
__device__ inline ushort_t f2b(float f) {  // RTNE
  uint_t u = __float_as_uint(f);
  uint_t r = (u + 0x7fffu + ((u >> 16) & 1u)) >> 16;
  return (ushort_t)r;
}
__device__ inline uint_t pk2(float a, float b) {
  return (uint_t)f2b(a) | ((uint_t)f2b(b) << 16);
}

// ================= CSR build via 2-pass bucket sort =================
// bucket = col >> 9 (512 nodes per bucket). NB <= 256 (N <= 131072).

__global__ __launch_bounds__(256) void bcount_k(const int* __restrict__ col,
                                                int* __restrict__ bcnt, int E, int NB) {
  __shared__ int h[256];
  int t = threadIdx.x;
  h[t] = 0;
  __syncthreads();
  int e0 = blockIdx.x * 8192;
#pragma unroll
  for (int j = 0; j < 32; ++j) {
    int e = e0 + j * 256 + t;
    if (e < E) atomicAdd(&h[col[e] >> 9], 1);
  }
  __syncthreads();
  if (t < NB && h[t] > 0) atomicAdd(&bcnt[t], h[t]);
}

__global__ __launch_bounds__(256) void bscan_k(const int* __restrict__ bcnt,
                                               int* __restrict__ bbase, int* __restrict__ cursor,
                                               int* __restrict__ offs, int NB, int N, int E) {
  __shared__ int sd[256];
  int t = threadIdx.x;
  int v = (t < NB) ? bcnt[t] : 0;
  int acc = v;
  sd[t] = v; __syncthreads();
  for (int off = 1; off < 256; off <<= 1) {
    int x = (t >= off) ? sd[t - off] : 0;
    __syncthreads();
    acc += x; sd[t] = acc;
    __syncthreads();
  }
  if (t < NB) { bbase[t] = acc - v; cursor[t] = acc - v; }
  if (t == 0) { bbase[NB] = E; offs[N] = E; }
}

__global__ __launch_bounds__(512) void bscatter_k(
    const int* __restrict__ row, const int* __restrict__ col, const float* __restrict__ ew,
    int* __restrict__ cursor, uint2* __restrict__ eout, int E, int NB) {
  __shared__ int h[256];
  __shared__ int lofs[256];
  __shared__ int lcur[256];
  __shared__ int gbase[256];
  __shared__ int sc[256];
  __shared__ uint2 stage[8192];
  __shared__ int addr[8192];
  int t = threadIdx.x;
  int e0 = blockIdx.x * 8192;
  int cnt = min(8192, E - e0);
  if (t < 256) h[t] = 0;
  __syncthreads();
#pragma unroll
  for (int j = 0; j < 16; ++j) {
    int e = e0 + j * 512 + t;
    if (e < E) atomicAdd(&h[col[e] >> 9], 1);
  }
  __syncthreads();
  int s = (t < 256) ? h[t] : 0;
  int acc = s;
  if (t < 256) sc[t] = s;
  __syncthreads();
  for (int off = 1; off < 256; off <<= 1) {
    int x = (t < 256 && t >= off) ? sc[t - off] : 0;
    __syncthreads();
    if (t < 256) { acc += x; sc[t] = acc; }
    __syncthreads();
  }
  if (t < NB && s > 0) gbase[t] = atomicAdd(&cursor[t], s);
  if (t < 256) { lofs[t] = acc - s; lcur[t] = acc - s; }
  __syncthreads();
#pragma unroll
  for (int j = 0; j < 16; ++j) {
    int e = e0 + j * 512 + t;
    if (e < E) {
      int c = col[e];
      int bk = c >> 9;
      int p = atomicAdd(&lcur[bk], 1);
      uint2 v;
      v.x = ((uint_t)(c & 511) << 17) | (uint_t)row[e];
      v.y = __float_as_uint(ew[e]);
      stage[p] = v;
      addr[p] = gbase[bk] + (p - lofs[bk]);
    }
  }
  __syncthreads();
  for (int i = t; i < cnt; i += 512) eout[addr[i]] = stage[i];
}

// per-bucket node sort (direct global scatter; block's 64KB window is L2-resident)
__global__ __launch_bounds__(512) void bsort_k(
    const uint2* __restrict__ ein, const int* __restrict__ bbase,
    int* __restrict__ offs, float* __restrict__ dinv, float* __restrict__ cinv,
    uint2* __restrict__ eout, int N) {
  __shared__ int h[512];
  __shared__ int lcur[512];
  __shared__ float degs[512];
  __shared__ int sd[512];
  int t = threadIdx.x, b = blockIdx.x;
  int base = bbase[b], end = bbase[b + 1];
  int cnt = end - base;
  int node0 = b << 9;
  h[t] = 0;
  degs[t] = 0.f;
  __syncthreads();
  for (int i = t; i < cnt; i += 512) {
    uint2 v = ein[base + i];
    int lc = v.x >> 17;
    atomicAdd(&h[lc], 1);
    atomicAdd(&degs[lc], __uint_as_float(v.y));
  }
  __syncthreads();
  int s = h[t];
  int acc = s;
  sd[t] = s; __syncthreads();
  for (int off = 1; off < 512; off <<= 1) {
    int x = (t >= off) ? sd[t - off] : 0;
    __syncthreads();
    acc += x; sd[t] = acc;
    __syncthreads();
  }
  int excl = acc - s;
  lcur[t] = excl;
  int node = node0 + t;
  if (node < N) {
    offs[node] = base + excl;
    float d = degs[t];
    dinv[node] = d > 0.f ? rsqrtf(d) : 0.f;
    cinv[node] = 1.0f / fmaxf((float)s, 1.f);
  }
  __syncthreads();
  for (int i = t; i < cnt; i += 512) {
    uint2 v = ein[base + i];
    int lc = v.x >> 17;
    int p = atomicAdd(&lcur[lc], 1);
    uint2 o;
    o.x = v.x & 0x1FFFF;
    o.y = v.y;
    eout[base + p] = o;
  }
}

// pack per-edge weights: {f16(dinv[row]*ew) | f16(ew)<<16}
__global__ void edgew_k(uint2* __restrict__ sedge, const float* __restrict__ dinv, int E) {
  int e = blockIdx.x * blockDim.x + threadIdx.x;
  if (e < E) {
    uint2 v = sedge[e];
    float ew = __uint_as_float(v.y);
    float wA = dinv[v.x] * ew;
    uint_t lo = (uint_t)__half_as_ushort(__float2half_rn(wA));
    uint_t hi = (uint_t)__half_as_ushort(__float2half_rn(ew));
    sedge[e].y = lo | (hi << 16);
  }
}

// ---------------- weight transpose+convert ----------------
// b<11: Wt[c][k] = bf16(W[k][c]) (128x128).  b==11: cls_wt[c][k] = bf16(cls_w[k*16+c]) (16x256)
struct WP { const float* p[12]; };
__global__ void wtp_k(WP wp, ushort_t* __restrict__ wt) {
  int b = blockIdx.x;
  int t = threadIdx.x;
  if (b < 11) {
    const float* W = wp.p[b];
    ushort_t* T = wt + (size_t)b * 128 * 128;
    for (int i = 0; i < 64; ++i) {
      int lin = i * 256 + t;
      int k = lin >> 7, c = lin & 127;
      T[c * 128 + k] = f2b(W[lin]);
    }
  } else {
    const float* W = wp.p[11];
    ushort_t* T = wt + (size_t)11 * 128 * 128;
    for (int i = 0; i < 16; ++i) {
      int lin = i * 256 + t;  // < 4096
      int c = lin >> 8, k = lin & 255;
      T[lin] = f2b(W[k * 16 + c]);
    }
  }
}

// ---------------- aggregation: half-wave per node, 8 edges/iter ----------------
__global__ __launch_bounds__(256) void agg_k(
    const uint_t* __restrict__ hp2, const uint2* __restrict__ sedge,
    const float* __restrict__ dinv, const float* __restrict__ cinv,
    const int* __restrict__ offs,
    uint_t* __restrict__ outA, uint_t* __restrict__ outS, int n) {
  int wid = threadIdx.x >> 6;
  int lane = threadIdx.x & 63;
  int half = lane >> 5, li = lane & 31;
  int node = blockIdx.x * 8 + wid * 2 + half;
  if (node >= n) return;
  int s0 = offs[node], e0 = offs[node + 1];
  const char* hpb = (const char*)hp2;
  uint_t libase = (uint_t)(li << 3);
  float a0 = 0.f, a1 = 0.f, a2 = 0.f, a3 = 0.f;
  float m0 = 0.f, m1 = 0.f, m2 = 0.f, m3 = 0.f;
  for (int p = s0; p < e0; p += 8) {
    uint2 ed[8];
#pragma unroll
    for (int j = 0; j < 8; ++j) {
      int k = p + j;
      ed[j] = sedge[k < e0 ? k : s0];
    }
#pragma unroll
    for (int j = 0; j < 8; ++j) {
      bool ok = (p + j < e0);
      uint_t w = ok ? ed[j].y : 0u;
      uint_t vo = (ed[j].x << 8) | libase;
      uint2 v = *(const uint2*)(hpb + vo);
      float wA = __half2float(__ushort_as_half((ushort_t)(w & 0xffff)));
      float wS = __half2float(__ushort_as_half((ushort_t)(w >> 16)));
      float f0 = blo(v.x), f1 = bhi(v.x), f2 = blo(v.y), f3 = bhi(v.y);
      a0 += wA * f0; a1 += wA * f1; a2 += wA * f2; a3 += wA * f3;
      m0 += wS * f0; m1 += wS * f1; m2 += wS * f2; m3 += wS * f3;
    }
  }
  float dn = dinv[node], cn = cinv[node];
  uint2 oA, oS;
  oA.x = pk2(dn * a0, dn * a1); oA.y = pk2(dn * a2, dn * a3);
  oS.x = pk2(cn * m0, cn * m1); oS.y = pk2(cn * m2, cn * m3);
  *(uint2*)&outA[(size_t)node * 64 + li * 2] = oA;
  *(uint2*)&outS[(size_t)node * 64 + li * 2] = oS;
}

// ---------------- GEMM building blocks ----------------
__device__ inline int swz(int r, int k) { return (r * 128 + k) ^ ((r & 7) << 3); }
__device__ inline int cswz(int r, int k) { return (r * 256 + k) ^ ((r & 7) << 3); }

__device__ inline void stage_tile(const ushort_t* __restrict__ A, ushort_t* lds,
                                  int rowBase, int wid, int lane) {
  int lr = lane >> 4, lchunk = lane & 15;
#ifdef HAS_GLL
#pragma unroll
  for (int i = 0; i < 8; ++i) {
    int r = wid * 32 + i * 4 + lr;
    int csrc = (lchunk ^ (r & 7)) << 4;
    const char* g = (const char*)A + (((size_t)(rowBase + r)) << 8) + csrc;
    char* l = (char*)lds + ((wid * 32 + i * 4) << 8);
    __builtin_amdgcn_global_load_lds((const __attribute__((address_space(1))) void*)g,
                                     (__attribute__((address_space(3))) void*)l, 16, 0, 0);
  }
#else
#pragma unroll
  for (int i = 0; i < 8; ++i) {
    int r = wid * 32 + i * 4 + lr;
    uint4 v = *(const uint4*)&A[((size_t)(rowBase + r)) * 128 + lchunk * 8];
    *(uint4*)&lds[swz(r, lchunk * 8)] = v;
  }
#endif
}

__device__ inline void stage_wait() {
#ifdef HAS_GLL
  asm volatile("s_waitcnt vmcnt(0)" ::: "memory");
#endif
}

__device__ inline bf16x8 ldw(const ushort_t* __restrict__ Wt, int wc, int nn, int k, int lane) {
  int c = wc * 64 + nn * 16 + (lane & 15);
  return *(const bf16x8*)&Wt[c * 128 + k * 32 + (lane >> 4) * 8];
}

__device__ inline bf16x8 lda(const ushort_t* lds, int wr, int m, int k, int lane) {
  return *(const bf16x8*)&lds[swz(wr * 64 + m * 16 + (lane & 15), k * 32 + (lane >> 4) * 8)];
}

template <int ACT>
__device__ inline void epilogue(f32x4 (&acc)[4][4], const float* __restrict__ bias,
                                ushort_t* __restrict__ out, int rowBase, int wr, int wc,
                                int lane, int nrows) {
#pragma unroll
  for (int m = 0; m < 4; ++m) {
    int gr0 = rowBase + wr * 64 + m * 16 + (lane >> 4) * 4;
#pragma unroll
    for (int nn = 0; nn < 4; ++nn) {
      int gc = wc * 64 + nn * 16 + (lane & 15);
      float bv = bias[gc];
#pragma unroll
      for (int j = 0; j < 4; ++j) {
        int gr = gr0 + j;
        if (gr < nrows) {
          float v = acc[m][nn][j] + bv;
          if (ACT == 1) v = fmaxf(v, 0.f);
          if (ACT == 2) v = v > 0.f ? v : (__expf(0.01f * v) - 1.f);
          out[(size_t)gr * 128 + gc] = f2b(v);
        }
      }
    }
  }
}

// ---------------- pre0: f32 input, single source ----------------
__global__ __launch_bounds__(256, 2) void pre0_k(
    const float* __restrict__ Xf, const ushort_t* __restrict__ Wt,
    const float* __restrict__ bias, ushort_t* __restrict__ out, int nrows) {
  __shared__ ushort_t As[128 * 128];
  int t = threadIdx.x, lane = t & 63, wid = t >> 6;
  int wr = wid >> 1, wc = wid & 1;
  int rowBase = blockIdx.x * 128;
#pragma unroll
  for (int i = 0; i < 16; ++i) {
    int f = t + i * 256;
    int r = f >> 5, q = f & 31;
    int gr = rowBase + r;
    float4 v = make_float4(0.f, 0.f, 0.f, 0.f);
    if (gr < nrows) v = *(const float4*)&Xf[(size_t)gr * 128 + q * 4];
    uint2 o;
    o.x = pk2(v.x, v.y);
    o.y = pk2(v.z, v.w);
    *(uint2*)&As[swz(r, q * 4)] = o;
  }
  __syncthreads();
  f32x4 acc[4][4] = {};
#pragma unroll
  for (int k = 0; k < 4; ++k) {
    bf16x8 af[4], wf[4];
#pragma unroll
    for (int m = 0; m < 4; ++m) af[m] = lda(As, wr, m, k, lane);
#pragma unroll
    for (int nn = 0; nn < 4; ++nn) wf[nn] = ldw(Wt, wc, nn, k, lane);
#pragma unroll
    for (int m = 0; m < 4; ++m)
#pragma unroll
      for (int nn = 0; nn < 4; ++nn)
        acc[m][nn] = __builtin_amdgcn_mfma_f32_16x16x32_bf16(af[m], wf[nn], acc[m][nn], 0, 0, 0);
  }
  epilogue<0>(acc, bias, out, rowBase, wr, wc, lane, nrows);
}

// ---------------- fused cell: h1=relu(X@WX+H@WXH+bX), h2=elu(lrelu(Y@WY+H@WYH+bY)),
// then TAIL: 0 -> outH = cat(h1,h2)@[WZ1;WZ2] + bZ (pre of next cell)
//            1 -> outL = log_softmax(cat(h1,h2)@cls_wt + bZ)
template <int TAIL>
__global__ __launch_bounds__(256, 2) void dualfused_k(
    const ushort_t* __restrict__ X, const ushort_t* __restrict__ Y,
    const ushort_t* __restrict__ H,
    const ushort_t* __restrict__ WX, const ushort_t* __restrict__ WXH,
    const ushort_t* __restrict__ WY, const ushort_t* __restrict__ WYH,
    const float* __restrict__ bX, const float* __restrict__ bY,
    const ushort_t* __restrict__ WZ1, const ushort_t* __restrict__ WZ2,
    const float* __restrict__ bZ,
    ushort_t* __restrict__ outH, float* __restrict__ outL, int nrows) {
  __shared__ ushort_t buf[2 * 128 * 128];  // 64KB
  ushort_t* Xs = buf;
  ushort_t* Hs = buf + 128 * 128;
  int t = threadIdx.x, lane = t & 63, wid = t >> 6;
  int wr = wid >> 1, wc = wid & 1;
  int rowBase = blockIdx.x * 128;

  stage_tile(X, Xs, rowBase, wid, lane);
  stage_tile(H, Hs, rowBase, wid, lane);
  stage_wait();
  __syncthreads();

  // phase 1: h1 -> packed bf16 register stash (relu applied)
  uint_t h1p[4][4][2];
  {
    f32x4 acc[4][4] = {};
#pragma unroll
    for (int k = 0; k < 4; ++k) {
      bf16x8 af[4], hf[4], wx[4], wh[4];
#pragma unroll
      for (int m = 0; m < 4; ++m) { af[m] = lda(Xs, wr, m, k, lane); hf[m] = lda(Hs, wr, m, k, lane); }
#pragma unroll
      for (int nn = 0; nn < 4; ++nn) { wx[nn] = ldw(WX, wc, nn, k, lane); wh[nn] = ldw(WXH, wc, nn, k, lane); }
#pragma unroll
      for (int m = 0; m < 4; ++m)
#pragma unroll
        for (int nn = 0; nn < 4; ++nn) {
          acc[m][nn] = __builtin_amdgcn_mfma_f32_16x16x32_bf16(af[m], wx[nn], acc[m][nn], 0, 0, 0);
          acc[m][nn] = __builtin_amdgcn_mfma_f32_16x16x32_bf16(hf[m], wh[nn], acc[m][nn], 0, 0, 0);
        }
    }
#pragma unroll
    for (int m = 0; m < 4; ++m)
#pragma unroll
      for (int nn = 0; nn < 4; ++nn) {
        float bv = bX[wc * 64 + nn * 16 + (lane & 15)];
        float v0 = fmaxf(acc[m][nn][0] + bv, 0.f);
        float v1 = fmaxf(acc[m][nn][1] + bv, 0.f);
        float v2 = fmaxf(acc[m][nn][2] + bv, 0.f);
        float v3 = fmaxf(acc[m][nn][3] + bv, 0.f);
        h1p[m][nn][0] = pk2(v0, v1);
        h1p[m][nn][1] = pk2(v2, v3);
      }
  }

  __syncthreads();  // Xs reads done
  stage_tile(Y, Xs, rowBase, wid, lane);
  stage_wait();
  __syncthreads();

  // phase 2: h2 in acc2
  f32x4 acc2[4][4] = {};
#pragma unroll
  for (int k = 0; k < 4; ++k) {
    bf16x8 af[4], hf[4], wy[4], wh[4];
#pragma unroll
    for (int m = 0; m < 4; ++m) { af[m] = lda(Xs, wr, m, k, lane); hf[m] = lda(Hs, wr, m, k, lane); }
#pragma unroll
    for (int nn = 0; nn < 4; ++nn) { wy[nn] = ldw(WY, wc, nn, k, lane); wh[nn] = ldw(WYH, wc, nn, k, lane); }
#pragma unroll
    for (int m = 0; m < 4; ++m)
#pragma unroll
      for (int nn = 0; nn < 4; ++nn) {
        acc2[m][nn] = __builtin_amdgcn_mfma_f32_16x16x32_bf16(af[m], wy[nn], acc2[m][nn], 0, 0, 0);
        acc2[m][nn] = __builtin_amdgcn_mfma_f32_16x16x32_bf16(hf[m], wh[nn], acc2[m][nn], 0, 0, 0);
      }
  }

  __syncthreads();  // everyone done reading Xs/Hs

  // build cat tile [128][256] bf16 (swizzled) in buf
#pragma unroll
  for (int m = 0; m < 4; ++m) {
    int r0 = wr * 64 + m * 16 + (lane >> 4) * 4;
#pragma unroll
    for (int nn = 0; nn < 4; ++nn) {
      int c = wc * 64 + nn * 16 + (lane & 15);
      float bv = bY[c];
#pragma unroll
      for (int j = 0; j < 4; ++j) {
        int r = r0 + j;
        ushort_t h1v = (ushort_t)((h1p[m][nn][j >> 1] >> ((j & 1) * 16)) & 0xffff);
        buf[cswz(r, c)] = h1v;
        float v = acc2[m][nn][j] + bv;
        v = v > 0.f ? v : (__expf(0.01f * v) - 1.f);
        buf[cswz(r, 128 + c)] = f2b(v);
      }
    }
  }
  __syncthreads();

  if (TAIL == 0) {
    f32x4 acc3[4][4] = {};
#pragma unroll
    for (int kk = 0; kk < 8; ++kk) {
      const ushort_t* WZ = (kk < 4) ? WZ1 : WZ2;
      int kl = kk & 3;
      bf16x8 af[4], wf[4];
#pragma unroll
      for (int m = 0; m < 4; ++m) {
        int r = wr * 64 + m * 16 + (lane & 15);
        af[m] = *(const bf16x8*)&buf[cswz(r, kk * 32 + (lane >> 4) * 8)];
      }
#pragma unroll
      for (int nn = 0; nn < 4; ++nn) wf[nn] = ldw(WZ, wc, nn, kl, lane);
#pragma unroll
      for (int m = 0; m < 4; ++m)
#pragma unroll
        for (int nn = 0; nn < 4; ++nn)
          acc3[m][nn] = __builtin_amdgcn_mfma_f32_16x16x32_bf16(af[m], wf[nn], acc3[m][nn], 0, 0, 0);
    }
    epilogue<0>(acc3, bZ, outH, rowBase, wr, wc, lane, nrows);
  } else {
    // cls: each wave handles 32 rows (2 m-tiles), B = cls_wt [16][256]
    f32x4 accc[2] = {};
#pragma unroll
    for (int kk = 0; kk < 8; ++kk) {
      bf16x8 bfr = *(const bf16x8*)&WZ1[(lane & 15) * 256 + kk * 32 + (lane >> 4) * 8];
#pragma unroll
      for (int mm = 0; mm < 2; ++mm) {
        int r = wid * 32 + mm * 16 + (lane & 15);
        bf16x8 af = *(const bf16x8*)&buf[cswz(r, kk * 32 + (lane >> 4) * 8)];
        accc[mm] = __builtin_amdgcn_mfma_f32_16x16x32_bf16(af, bfr, accc[mm], 0, 0, 0);
      }
    }
    float bc = bZ[lane & 15];
#pragma unroll
    for (int mm = 0; mm < 2; ++mm) {
#pragma unroll
      for (int j = 0; j < 4; ++j) {
        float lg = accc[mm][j] + bc;
        float mx = lg;
        for (int d = 1; d < 16; d <<= 1) mx = fmaxf(mx, __shfl_xor(mx, d));
        float ex = __expf(lg - mx);
        float sum = ex;
        for (int d = 1; d < 16; d <<= 1) sum += __shfl_xor(sum, d);
        float r_ = (lg - mx) - logf(sum);
        int grow = rowBase + wid * 32 + mm * 16 + (lane >> 4) * 4 + j;
        if (grow < nrows) outL[grow * 16 + (lane & 15)] = r_;
      }
    }
  }
}

// ---------------- launch ----------------

extern "C" void kernel_launch(void* const* d_in, const int* in_sizes, int n_in,
                              void* d_out, int out_size, void* d_ws, size_t ws_size,
                              hipStream_t stream) {
  const float* x        = (const float*)d_in[0];
  const int*   eidx     = (const int*)d_in[1];
  const float* ew       = (const float*)d_in[2];
  const float* pre_w0   = (const float*)d_in[3];
  const float* pre_b0   = (const float*)d_in[4];
  const float* arma_w0  = (const float*)d_in[5];
  const float* arma_v0  = (const float*)d_in[6];
  const float* arma_b0  = (const float*)d_in[7];
  const float* sage_wl0 = (const float*)d_in[8];
  const float* sage_bl0 = (const float*)d_in[9];
  const float* sage_wr0 = (const float*)d_in[10];
  const float* pre_w1   = (const float*)d_in[11];
  const float* pre_b1   = (const float*)d_in[12];
  const float* arma_w1  = (const float*)d_in[13];
  const float* arma_v1  = (const float*)d_in[14];
  const float* arma_b1  = (const float*)d_in[15];
  const float* sage_wl1 = (const float*)d_in[16];
  const float* sage_bl1 = (const float*)d_in[17];
  const float* sage_wr1 = (const float*)d_in[18];
  const float* cls_w    = (const float*)d_in[19];
  const float* cls_b    = (const float*)d_in[20];

  const int N = in_sizes[0] / 128;
  const int E = in_sizes[2];
  const int N_pad = ((N + 127) / 128) * 128;
  const int NB = (N + 511) >> 9;
  const int* row = eidx;
  const int* col = eidx + E;

  char* p = (char*)d_ws;
  auto carve = [&](size_t bytes) { char* q = p; p += (bytes + 255) & ~(size_t)255; return q; };
  ushort_t* hp    = (ushort_t*)carve((size_t)N_pad * 128 * 2);
  ushort_t* bufA  = (ushort_t*)carve((size_t)N_pad * 128 * 2);
  ushort_t* bufS  = (ushort_t*)carve((size_t)N_pad * 128 * 2);
  ushort_t* wt    = (ushort_t*)carve(((size_t)11 * 128 * 128 + 16 * 256) * 2);
  uint2*  sedge  = (uint2*)carve((size_t)E * 8);
  uint2*  sedgeT = (uint2*)carve((size_t)E * 8);
  float*  dinv  = (float*)carve((size_t)N * 4);
  float*  cinv  = (float*)carve((size_t)N * 4);
  int*    offs  = (int*)carve((size_t)(N + 1) * 4);
  int*    bcnt  = (int*)carve((size_t)256 * 4);
  int*    bbase = (int*)carve((size_t)257 * 4);
  int*    cursor= (int*)carve((size_t)256 * 4);

  hipMemsetAsync(bcnt, 0, (size_t)256 * 4, stream);

  const int gE = (E + 8191) / 8192;
  bcount_k<<<gE, 256, 0, stream>>>(col, bcnt, E, NB);
  bscan_k<<<1, 256, 0, stream>>>(bcnt, bbase, cursor, offs, NB, N, E);
  bscatter_k<<<gE, 512, 0, stream>>>(row, col, ew, cursor, sedgeT, E, NB);
  bsort_k<<<NB, 512, 0, stream>>>(sedgeT, bbase, offs, dinv, cinv, sedge, N);
  edgew_k<<<(E + 255) / 256, 256, 0, stream>>>(sedge, dinv, E);

  WP wp;
  wp.p[0] = pre_w0;  wp.p[1] = arma_w0; wp.p[2] = arma_v0;
  wp.p[3] = sage_wl0; wp.p[4] = sage_wr0;
  wp.p[5] = pre_w1;  wp.p[6] = pre_w1 + 128 * 128;
  wp.p[7] = arma_w1; wp.p[8] = arma_v1;
  wp.p[9] = sage_wl1; wp.p[10] = sage_wr1;
  wp.p[11] = cls_w;
  wtp_k<<<12, 256, 0, stream>>>(wp, wt);

  const int gB = (N + 127) / 128;
  const int gA = (N + 7) / 8;
  auto WT = [&](int i) { return wt + (size_t)i * 128 * 128; };

  // ---- cell 0 (+ fused pre of cell 1) ----
  pre0_k<<<gB, 256, 0, stream>>>(x, WT(0), pre_b0, hp, N);
  agg_k<<<gA, 256, 0, stream>>>((const uint_t*)hp, sedge, dinv, cinv, offs, (uint_t*)bufA, (uint_t*)bufS, N);
  dualfused_k<0><<<gB, 256, 0, stream>>>(bufA, bufS, hp, WT(1), WT(2), WT(3), WT(4),
                                         arma_b0, sage_bl0, WT(5), WT(6), pre_b1,
                                         hp, nullptr, N);
  // ---- cell 1 (+ fused classifier) ----
  agg_k<<<gA, 256, 0, stream>>>((const uint_t*)hp, sedge, dinv, cinv, offs, (uint_t*)bufA, (uint_t*)bufS, N);
  dualfused_k<1><<<gB, 256, 0, stream>>>(bufA, bufS, hp, WT(7), WT(8), WT(9), WT(10),
                                         arma_b1, sage_bl1, WT(11), nullptr, cls_b,
                                         nullptr, (float*)d_out, N);
}